// Round 3
// baseline (25426.898 us; speedup 1.0000x reference)
//
#include <hip/hip_runtime.h>

typedef unsigned int uint;
typedef unsigned short ushort;
typedef __attribute__((ext_vector_type(8))) short s16x8;
typedef __attribute__((ext_vector_type(4))) float f32x4;
typedef __attribute__((ext_vector_type(4))) uint u32x4;

// problem dims (fixed)
#define SEQ 1024
#define BATCH 64
#define INDIM 512
#define HID 1024

// ---- workspace layout (bytes) ----
#define OFF_BUF   0ull
#define SZ_BUF    (65536ull * 1024ull * 2ull)           // c0 -> r0 (in-place), bf16
#define OFF_W0B   (OFF_BUF + SZ_BUF)                    // W_ih0 bf16 (1024x512)
#define OFF_WH0B  (OFF_W0B  + 1048576ull)               // W_hh0 bf16 (1024x1024)
#define OFF_W1B   (OFF_WH0B + 2097152ull)               // W_ih1 bf16
#define OFF_WH1B  (OFF_W1B  + 2097152ull)               // W_hh1 bf16
#define OFF_HINIT (OFF_WH1B + 2097152ull)               // hidden bf16 [2][64][1024]
#define OFF_HDB1  (OFF_HINIT + 262144ull)               // L1 h double buffer [2][64][1024] bf16
#define OFF_FLG   (OFF_HDB1 + 262144ull)                // flags [2][4][1024][4] u32
#define OFF_PPART (OFF_FLG + 131072ull)                 // pooled partials [4][1024][1024] f32
#define WS_NEEDED (OFF_PPART + 16777216ull)

__device__ __forceinline__ ushort f2bf(float f) {
    uint u = __float_as_uint(f);
    uint r = (u + 0x7fffu + ((u >> 16) & 1u)) >> 16;
    return (ushort)r;
}
__device__ __forceinline__ float bf2f(ushort h) {
    return __uint_as_float(((uint)h) << 16);
}

// ---------------- prep: convert weights/hidden to bf16, zero flags ----------------
__global__ void k_prep(const float* Wih0, const float* Whh0, const float* Wih1,
                       const float* Whh1, const float* hid, char* ws) {
    ushort* w0  = (ushort*)(ws + OFF_W0B);
    ushort* wh0 = (ushort*)(ws + OFF_WH0B);
    ushort* w1  = (ushort*)(ws + OFF_W1B);
    ushort* wh1 = (ushort*)(ws + OFF_WH1B);
    ushort* hi  = (ushort*)(ws + OFF_HINIT);
    uint*   flg = (uint*)(ws + OFF_FLG);
    const long long total = 524288 + 3 * 1048576 + 131072 + 32768;
    for (long long i = (long long)blockIdx.x * 256 + threadIdx.x; i < total;
         i += (long long)gridDim.x * 256) {
        long long j = i;
        if (j < 524288)  { w0[j]  = f2bf(Wih0[j]); continue; }  j -= 524288;
        if (j < 1048576) { wh0[j] = f2bf(Whh0[j]); continue; }  j -= 1048576;
        if (j < 1048576) { w1[j]  = f2bf(Wih1[j]); continue; }  j -= 1048576;
        if (j < 1048576) { wh1[j] = f2bf(Whh1[j]); continue; }  j -= 1048576;
        if (j < 131072)  { hi[j]  = f2bf(hid[j]);  continue; }  j -= 131072;
        flg[j] = 0u;
    }
}

// ---------------- proj0: c0 = x @ W_ih0^T + b_ih0 + b_hh0 (bf16 out) ----------------
// grid 4096 x 256.  tile: M=64 (4 waves x 16 rows), N=256, K=512.
__launch_bounds__(256)
__global__ void k_proj0(const float* __restrict__ x, const float* __restrict__ bih,
                        const float* __restrict__ bhh, char* ws) {
    const ushort* W = (const ushort*)(ws + OFF_W0B);
    ushort* cbuf = (ushort*)(ws + OFF_BUF);
    int bx = blockIdx.x;
    int mtile = bx >> 2, ntile = bx & 3;
    int tid = threadIdx.x, w = tid >> 6, l = tid & 63;
    int lr = l & 15, lq = l >> 4;
    int arow = mtile * 64 + w * 16 + lr;

    f32x4 acc[16];
#pragma unroll
    for (int i = 0; i < 16; i++) acc[i] = (f32x4){0.f, 0.f, 0.f, 0.f};

    for (int kc = 0; kc < 16; kc++) {
        int k0 = kc * 32 + lq * 8;
        const f32x4* ap = (const f32x4*)(x + (long long)arow * 512 + k0);
        f32x4 a0 = ap[0], a1 = ap[1];
        s16x8 a;
        a[0] = (short)f2bf(a0[0]); a[1] = (short)f2bf(a0[1]);
        a[2] = (short)f2bf(a0[2]); a[3] = (short)f2bf(a0[3]);
        a[4] = (short)f2bf(a1[0]); a[5] = (short)f2bf(a1[1]);
        a[6] = (short)f2bf(a1[2]); a[7] = (short)f2bf(a1[3]);
#pragma unroll
        for (int nf = 0; nf < 16; nf++) {
            int col = ntile * 256 + nf * 16 + lr;
            s16x8 b = *(const s16x8*)(W + (long long)col * 512 + k0);
            acc[nf] = __builtin_amdgcn_mfma_f32_16x16x32_bf16(a, b, acc[nf], 0, 0, 0);
        }
    }
#pragma unroll
    for (int nf = 0; nf < 16; nf++) {
        int col = ntile * 256 + nf * 16 + lr;
        float bb = bih[col] + bhh[col];
#pragma unroll
        for (int j = 0; j < 4; j++) {
            int row = mtile * 64 + w * 16 + lq * 4 + j;
            cbuf[(long long)row * 1024 + col] = f2bf(acc[nf][j] + bb);
        }
    }
}

// ---------------- fused recurrence (both layers, pipelined) ----------------
// grid 32 x 1024.  wid>>4 = layer; g = wid&3 (batch group of 16); islice = (wid>>2)&3
// (256 hidden cols per WG).  Weights register-resident.  Per-producer flag slots.
// L0: h_t = tanh(c0[t] + h_{t-1} @ Whh0^T), h stream stored in cbuf (r0).
// L1: h_t = tanh(r0[t] @ Wih1^T + b + h_{t-1} @ Whh1^T), pooled sums to ppart.
__launch_bounds__(1024)
__global__ void k_recf(const float* __restrict__ bih1, const float* __restrict__ bhh1,
                       char* ws) {
    int wid = blockIdx.x;
    int layer = wid >> 4;
    int g = wid & 3;
    int islice = (wid >> 2) & 3;
    int tid = threadIdx.x;
    int wv = tid >> 6, l = tid & 63, lr = l & 15, lq = l >> 4;
    int mycol = islice * 256 + wv * 16 + lr;

    ushort* cbuf = (ushort*)(ws + OFF_BUF);
    ushort* hdb1 = (ushort*)(ws + OFF_HDB1);
    const ushort* hinit = (const ushort*)(ws + OFF_HINIT) + layer * 65536;
    uint* flg = (uint*)(ws + OFF_FLG);             // [layer][g][t][4]
    float* ppart = (float*)(ws + OFF_PPART);
    const ushort* WhhB = (const ushort*)(ws + (layer ? OFF_WH1B : OFF_WH0B));
    const ushort* WxB  = (const ushort*)(ws + OFF_W1B);

    __shared__ __align__(16) char lds[65536];
    char* ldsH = lds;
    char* ldsX = lds + 32768;

    // preload weights (B-fragments): B[k][n] = W[n][k] -> row mycol, consecutive k
    s16x8 wh[32], wx[32];
#pragma unroll
    for (int kc = 0; kc < 32; kc++)
        wh[kc] = *(const s16x8*)(WhhB + (long long)mycol * 1024 + kc * 32 + lq * 8);
    if (layer) {
#pragma unroll
        for (int kc = 0; kc < 32; kc++)
            wx[kc] = *(const s16x8*)(WxB + (long long)mycol * 1024 + kc * 32 + lq * 8);
    }
    float bb = layer ? (bih1[mycol] + bhh1[mycol]) : 0.f;

    for (int t = 0; t < 1024; t++) {
        int cbase = (t * 64 + g * 16) * 1024;

        // L0: prefetch this step's c0 (own cols only -> own 128B lines) before gate
        ushort cf[4];
        if (!layer) {
#pragma unroll
            for (int j = 0; j < 4; j++)
                cf[j] = cbuf[cbase + (lq * 4 + j) * 1024 + mycol];
        }

        // ---- gate: wave 0 polls per-producer flags ----
        if (tid < 64) {
            const uint* fp = nullptr;
            if (layer == 0) {
                if (t > 0 && l < 4) fp = &flg[(g * 1024 + (t - 1)) * 4 + l];
            } else {
                if (l < 4) fp = &flg[(g * 1024 + t) * 4 + l];
                else if (l < 8 && t > 0) fp = &flg[((4 + g) * 1024 + (t - 1)) * 4 + (l - 4)];
            }
            if (__any(fp != nullptr)) {
                for (;;) {
                    uint v = fp ? __hip_atomic_load(fp, __ATOMIC_RELAXED,
                                                    __HIP_MEMORY_SCOPE_AGENT) : 1u;
                    if (__all(v != 0u)) break;
                    __builtin_amdgcn_s_sleep(1);
                }
                if (l == 0)
                    (void)__hip_atomic_load(&flg[0], __ATOMIC_ACQUIRE,
                                            __HIP_MEMORY_SCOPE_AGENT);
            }
        }
        __syncthreads();

        // ---- stage h_{t-1} (16 x 1024 bf16, XOR-swizzled) ----
        const ushort* hsrc = (t == 0) ? (hinit + g * 16 * 1024)
                           : (layer ? (hdb1 + ((t - 1) & 1) * 65536 + g * 16 * 1024)
                                    : (cbuf + ((t - 1) * 64 + g * 16) * 1024));
#pragma unroll
        for (int i = 0; i < 2; i++) {
            int off = tid * 16 + i * 16384;
            u32x4 v = *(const u32x4*)((const char*)hsrc + off);
            int row = off >> 11;
            int sw = (off & 2047) ^ ((row & 7) << 4);
            *(u32x4*)(ldsH + row * 2048 + sw) = v;
        }
        if (layer) {
            const ushort* xsrc = cbuf + cbase;  // r0[t], gated by L0 flags
#pragma unroll
            for (int i = 0; i < 2; i++) {
                int off = tid * 16 + i * 16384;
                u32x4 v = *(const u32x4*)((const char*)xsrc + off);
                int row = off >> 11;
                int sw = (off & 2047) ^ ((row & 7) << 4);
                *(u32x4*)(ldsX + row * 2048 + sw) = v;
            }
        }
        __syncthreads();

        // ---- compute (two accumulator chains per GEMM for latency ILP) ----
        f32x4 a0 = (f32x4){0.f, 0.f, 0.f, 0.f}, a1 = (f32x4){0.f, 0.f, 0.f, 0.f};
#pragma unroll
        for (int kc = 0; kc < 32; kc += 2) {
            int b0 = (kc * 64 + lq * 16) ^ ((lr & 7) << 4);
            int b1 = ((kc + 1) * 64 + lq * 16) ^ ((lr & 7) << 4);
            s16x8 f0 = *(const s16x8*)(ldsH + lr * 2048 + b0);
            s16x8 f1 = *(const s16x8*)(ldsH + lr * 2048 + b1);
            a0 = __builtin_amdgcn_mfma_f32_16x16x32_bf16(f0, wh[kc], a0, 0, 0, 0);
            a1 = __builtin_amdgcn_mfma_f32_16x16x32_bf16(f1, wh[kc + 1], a1, 0, 0, 0);
        }
        if (layer) {
#pragma unroll
            for (int kc = 0; kc < 32; kc += 2) {
                int b0 = (kc * 64 + lq * 16) ^ ((lr & 7) << 4);
                int b1 = ((kc + 1) * 64 + lq * 16) ^ ((lr & 7) << 4);
                s16x8 f0 = *(const s16x8*)(ldsX + lr * 2048 + b0);
                s16x8 f1 = *(const s16x8*)(ldsX + lr * 2048 + b1);
                a0 = __builtin_amdgcn_mfma_f32_16x16x32_bf16(f0, wx[kc], a0, 0, 0, 0);
                a1 = __builtin_amdgcn_mfma_f32_16x16x32_bf16(f1, wx[kc + 1], a1, 0, 0, 0);
            }
        }

        float hn[4];
#pragma unroll
        for (int j = 0; j < 4; j++) {
            float z = a0[j] + a1[j] + (layer ? bb : bf2f(cf[j]));
            z = fminf(fmaxf(z, -30.f), 30.f);
            float e = __expf(2.f * z);
            hn[j] = (e - 1.f) / (e + 1.f);
        }

        // ---- publish ----
        if (!layer) {
#pragma unroll
            for (int j = 0; j < 4; j++)
                cbuf[cbase + (lq * 4 + j) * 1024 + mycol] = f2bf(hn[j]);
        } else {
            ushort* hdst = hdb1 + (t & 1) * 65536 + g * 16 * 1024;
#pragma unroll
            for (int j = 0; j < 4; j++)
                hdst[(lq * 4 + j) * 1024 + mycol] = f2bf(hn[j]);
            float s = hn[0] + hn[1] + hn[2] + hn[3];
            s += __shfl_xor(s, 16);
            s += __shfl_xor(s, 32);
            if (l < 16) ppart[(g * 1024 + t) * 1024 + mycol] = s;
        }

        __syncthreads();  // all waves' stores drained (vmcnt(0) before barrier)
        if (tid == 0)
            __hip_atomic_store(&flg[((layer * 4 + g) * 1024 + t) * 4 + islice], 1u,
                               __ATOMIC_RELEASE, __HIP_MEMORY_SCOPE_AGENT);
    }
}

// ---------------- head: pooled mean -> FC1+ReLU -> FC2+sigmoid ----------------
// grid 128 x 256; each WG handles 8 sequence positions.
__launch_bounds__(256)
__global__ void k_head(const float* __restrict__ W1, const float* __restrict__ b1,
                       const float* __restrict__ W2, const float* __restrict__ b2,
                       char* ws, float* __restrict__ out) {
    const float* pp = (const float*)(ws + OFF_PPART);
    int bx = blockIdx.x;
    int t0 = bx * 8;
    int tid = threadIdx.x;

    __shared__ float pl[8][1024];
    __shared__ float red[256][8];

    for (int i = tid; i < 8192; i += 256) {
        int tt = i >> 10, k = i & 1023;
        int base = (t0 + tt) * 1024 + k;
        float s = pp[base] + pp[1048576 + base] + pp[2097152 + base] + pp[3145728 + base];
        pl[tt][k] = s * (1.f / 64.f);
    }
    __syncthreads();

    float po[8];
#pragma unroll
    for (int tt = 0; tt < 8; tt++) po[tt] = 0.f;

    for (int jj = 0; jj < 2; jj++) {
        int j = tid + jj * 256;
        float accv[8];
        float bias = b1[j];
#pragma unroll
        for (int tt = 0; tt < 8; tt++) accv[tt] = bias;
        const float* wr = W1 + (long long)j * 1024;
        for (int k = 0; k < 1024; k += 8) {
            f32x4 wa = *(const f32x4*)(wr + k);
            f32x4 wb = *(const f32x4*)(wr + k + 4);
#pragma unroll
            for (int tt = 0; tt < 8; tt++) {
                accv[tt] += pl[tt][k] * wa[0] + pl[tt][k + 1] * wa[1] +
                            pl[tt][k + 2] * wa[2] + pl[tt][k + 3] * wa[3] +
                            pl[tt][k + 4] * wb[0] + pl[tt][k + 5] * wb[1] +
                            pl[tt][k + 6] * wb[2] + pl[tt][k + 7] * wb[3];
            }
        }
        float w2 = W2[j];
#pragma unroll
        for (int tt = 0; tt < 8; tt++) po[tt] += fmaxf(accv[tt], 0.f) * w2;
    }

#pragma unroll
    for (int tt = 0; tt < 8; tt++) red[tid][tt] = po[tt];
    __syncthreads();
    for (int st = 128; st >= 1; st >>= 1) {
        if (tid < st) {
#pragma unroll
            for (int tt = 0; tt < 8; tt++) red[tid][tt] += red[tid + st][tt];
        }
        __syncthreads();
    }
    if (tid < 8) out[t0 + tid] = 1.f / (1.f + __expf(-(red[0][tid] + b2[0])));
}

extern "C" void kernel_launch(void* const* d_in, const int* in_sizes, int n_in,
                              void* d_out, int out_size, void* d_ws, size_t ws_size,
                              hipStream_t stream) {
    const float* x    = (const float*)d_in[0];
    const float* hid  = (const float*)d_in[1];
    const float* Wih0 = (const float*)d_in[2];
    const float* Whh0 = (const float*)d_in[3];
    const float* bih0 = (const float*)d_in[4];
    const float* bhh0 = (const float*)d_in[5];
    const float* Wih1 = (const float*)d_in[6];
    const float* Whh1 = (const float*)d_in[7];
    const float* bih1 = (const float*)d_in[8];
    const float* bhh1 = (const float*)d_in[9];
    const float* W1   = (const float*)d_in[10];
    const float* b1   = (const float*)d_in[11];
    const float* W2   = (const float*)d_in[12];
    const float* b2   = (const float*)d_in[13];
    char* ws = (char*)d_ws;
    float* out = (float*)d_out;

    hipLaunchKernelGGL(k_prep, dim3(1024), dim3(256), 0, stream,
                       Wih0, Whh0, Wih1, Whh1, hid, ws);
    hipLaunchKernelGGL(k_proj0, dim3(4096), dim3(256), 0, stream, x, bih0, bhh0, ws);
    hipLaunchKernelGGL(k_recf, dim3(32), dim3(1024), 0, stream, bih1, bhh1, ws);
    hipLaunchKernelGGL(k_head, dim3(128), dim3(256), 0, stream, W1, b1, W2, b2, ws, out);
}

// Round 4
// 15246.910 us; speedup vs baseline: 1.6677x; 1.6677x over previous
//
#include <hip/hip_runtime.h>

typedef unsigned int uint;
typedef unsigned short ushort;
typedef __attribute__((ext_vector_type(8))) short s16x8;
typedef __attribute__((ext_vector_type(4))) float f32x4;
typedef __attribute__((ext_vector_type(4))) uint u32x4;

// problem dims (fixed)
#define SEQ 1024
#define BATCH 64
#define INDIM 512
#define HID 1024

// ---- workspace layout (bytes) ----
#define OFF_BUF   0ull
#define SZ_BUF    (65536ull * 1024ull * 2ull)           // c0 -> r0 (in-place), bf16
#define OFF_W0B   (OFF_BUF + SZ_BUF)                    // W_ih0 bf16 (1024x512)
#define OFF_WH0B  (OFF_W0B  + 1048576ull)               // W_hh0 bf16 (1024x1024)
#define OFF_W1B   (OFF_WH0B + 2097152ull)               // W_ih1 bf16
#define OFF_WH1B  (OFF_W1B  + 2097152ull)               // W_hh1 bf16
#define OFF_HINIT (OFF_WH1B + 2097152ull)               // hidden bf16 [2][64][1024]
#define OFF_HDB1  (OFF_HINIT + 262144ull)               // L1 h double buffer [2][64][1024] bf16
#define OFF_FLG   (OFF_HDB1 + 262144ull)                // flags [2][4][16] u32 monotone (region 128KB)
#define OFF_PPART (OFF_FLG + 131072ull)                 // pooled partials [4][1024][1024] f32
#define WS_NEEDED (OFF_PPART + 16777216ull)

__device__ __forceinline__ ushort f2bf(float f) {
    uint u = __float_as_uint(f);
    uint r = (u + 0x7fffu + ((u >> 16) & 1u)) >> 16;
    return (ushort)r;
}
__device__ __forceinline__ float bf2f(ushort h) {
    return __uint_as_float(((uint)h) << 16);
}

// wave0 gate: lanes 0..15 poll base[l] until >= tgt (monotone counters)
__device__ __forceinline__ void gate_wave(const uint* base, int l, uint tgt) {
    const uint* fp = (l < 16) ? base + l : nullptr;
    uint mytgt = (l < 16) ? tgt : 0u;
    for (;;) {
        uint v = fp ? __hip_atomic_load(fp, __ATOMIC_RELAXED, __HIP_MEMORY_SCOPE_AGENT) : 0u;
        if (__all(v >= mytgt)) break;
        __builtin_amdgcn_s_sleep(1);
    }
}

// ---------------- prep: convert weights/hidden to bf16, zero flags ----------------
__global__ void k_prep(const float* Wih0, const float* Whh0, const float* Wih1,
                       const float* Whh1, const float* hid, char* ws) {
    ushort* w0  = (ushort*)(ws + OFF_W0B);
    ushort* wh0 = (ushort*)(ws + OFF_WH0B);
    ushort* w1  = (ushort*)(ws + OFF_W1B);
    ushort* wh1 = (ushort*)(ws + OFF_WH1B);
    ushort* hi  = (ushort*)(ws + OFF_HINIT);
    uint*   flg = (uint*)(ws + OFF_FLG);
    const long long total = 524288 + 3 * 1048576 + 131072 + 32768;
    for (long long i = (long long)blockIdx.x * 256 + threadIdx.x; i < total;
         i += (long long)gridDim.x * 256) {
        long long j = i;
        if (j < 524288)  { w0[j]  = f2bf(Wih0[j]); continue; }  j -= 524288;
        if (j < 1048576) { wh0[j] = f2bf(Whh0[j]); continue; }  j -= 1048576;
        if (j < 1048576) { w1[j]  = f2bf(Wih1[j]); continue; }  j -= 1048576;
        if (j < 1048576) { wh1[j] = f2bf(Whh1[j]); continue; }  j -= 1048576;
        if (j < 131072)  { hi[j]  = f2bf(hid[j]);  continue; }  j -= 131072;
        flg[j] = 0u;
    }
}

// ---------------- proj0: c0 = x @ W_ih0^T + b_ih0 + b_hh0 (bf16 out) ----------------
__launch_bounds__(256)
__global__ void k_proj0(const float* __restrict__ x, const float* __restrict__ bih,
                        const float* __restrict__ bhh, char* ws) {
    const ushort* W = (const ushort*)(ws + OFF_W0B);
    ushort* cbuf = (ushort*)(ws + OFF_BUF);
    int bx = blockIdx.x;
    int mtile = bx >> 2, ntile = bx & 3;
    int tid = threadIdx.x, w = tid >> 6, l = tid & 63;
    int lr = l & 15, lq = l >> 4;
    int arow = mtile * 64 + w * 16 + lr;

    f32x4 acc[16];
#pragma unroll
    for (int i = 0; i < 16; i++) acc[i] = (f32x4){0.f, 0.f, 0.f, 0.f};

    for (int kc = 0; kc < 16; kc++) {
        int k0 = kc * 32 + lq * 8;
        const f32x4* ap = (const f32x4*)(x + (long long)arow * 512 + k0);
        f32x4 a0 = ap[0], a1 = ap[1];
        s16x8 a;
        a[0] = (short)f2bf(a0[0]); a[1] = (short)f2bf(a0[1]);
        a[2] = (short)f2bf(a0[2]); a[3] = (short)f2bf(a0[3]);
        a[4] = (short)f2bf(a1[0]); a[5] = (short)f2bf(a1[1]);
        a[6] = (short)f2bf(a1[2]); a[7] = (short)f2bf(a1[3]);
#pragma unroll
        for (int nf = 0; nf < 16; nf++) {
            int col = ntile * 256 + nf * 16 + lr;
            s16x8 b = *(const s16x8*)(W + (long long)col * 512 + k0);
            acc[nf] = __builtin_amdgcn_mfma_f32_16x16x32_bf16(a, b, acc[nf], 0, 0, 0);
        }
    }
#pragma unroll
    for (int nf = 0; nf < 16; nf++) {
        int col = ntile * 256 + nf * 16 + lr;
        float bb = bih[col] + bhh[col];
#pragma unroll
        for (int j = 0; j < 4; j++) {
            int row = mtile * 64 + w * 16 + lq * 4 + j;
            cbuf[(long long)row * 1024 + col] = f2bf(acc[nf][j] + bb);
        }
    }
}

// ---------------- fused recurrence (both layers, pipelined) ----------------
// grid 128 x 256.  xcd = wgid&7 -> XCD-local groups: L0 groups on XCD 0..3,
// L1 groups on XCD 4..7.  slice = wgid>>3 (16 slices x 64 cols).
// Weights as separate __restrict__ args => loop-invariant loads hoisted into VGPRs.
// L0: h_t = tanh(c0[t] + h @ Whh0^T); r0 published in place over c0.
// L1: h_t = tanh(r0[t] @ Wih1^T + b + h @ Whh1^T); pooled sums to ppart.
__launch_bounds__(256, 1)
__global__ void k_recf(const ushort* __restrict__ wh0p, const ushort* __restrict__ wh1p,
                       const ushort* __restrict__ wxp,
                       ushort* __restrict__ cbuf, ushort* __restrict__ hdb1,
                       const ushort* __restrict__ hinitb, uint* __restrict__ flg,
                       float* __restrict__ ppart,
                       const float* __restrict__ bih1, const float* __restrict__ bhh1) {
    int wgid = blockIdx.x;
    int xcd = wgid & 7, slice = wgid >> 3;
    int layer = xcd >> 2, g = xcd & 3;
    int tid = threadIdx.x;
    int l = tid & 63, wv = tid >> 6, lr = l & 15, lq = l >> 4;
    int mycol = slice * 64 + wv * 16 + lr;

    const ushort* WhhB = layer ? wh1p : wh0p;
    uint* flgOwn = flg + (layer * 4 + g) * 16;
    uint* flgDep = flg + g * 16;  // L0 flags (L1's r0 dependency)
    const ushort* hinit = hinitb + layer * 65536 + g * 16 * 1024;

    __shared__ __align__(16) char lds[65536];
    char* ldsH = lds;
    char* ldsX = lds + 32768;

    // register-resident weights (128 VGPR each set)
    s16x8 wh[32], wx[32];
#pragma unroll
    for (int kc = 0; kc < 32; kc++)
        wh[kc] = *(const s16x8*)(WhhB + (long long)mycol * 1024 + kc * 32 + lq * 8);
    if (layer) {
#pragma unroll
        for (int kc = 0; kc < 32; kc++)
            wx[kc] = *(const s16x8*)(wxp + (long long)mycol * 1024 + kc * 32 + lq * 8);
    }
    float bb = layer ? (bih1[mycol] + bhh1[mycol]) : 0.f;

    for (int t = 0; t < 1024; t++) {
        int cbase = (t * 64 + g * 16) * 1024;

        f32x4 ac[4];
#pragma unroll
        for (int u = 0; u < 4; u++) ac[u] = (f32x4){0.f, 0.f, 0.f, 0.f};

        ushort cf[4];
        if (!layer) {
            // prefetch own-col c0[t] (independent of recurrence) before gating
#pragma unroll
            for (int j = 0; j < 4; j++)
                cf[j] = cbuf[cbase + (lq * 4 + j) * 1024 + mycol];
        } else {
            // ---- gate A: r0[t] published by L0 group g ----
            if (tid < 64) gate_wave(flgDep, l, (uint)(t + 1));
            __syncthreads();
            __builtin_amdgcn_fence(__ATOMIC_ACQUIRE, "agent");
            const ushort* xsrc = cbuf + cbase;
#pragma unroll
            for (int i = 0; i < 8; i++) {
                int off = tid * 16 + i * 4096;
                u32x4 v = *(const u32x4*)((const char*)xsrc + off);
                int row = off >> 11;
                int sw = (off & 2047) ^ ((row & 7) << 4);
                *(u32x4*)(ldsX + row * 2048 + sw) = v;
            }
            __syncthreads();
            // Wih1 GEMM overlaps the wait for h1[t-1]
#pragma unroll
            for (int kc = 0; kc < 32; kc += 4) {
#pragma unroll
                for (int u = 0; u < 4; u++) {
                    int bo = ((kc + u) * 64 + lq * 16) ^ ((lr & 7) << 4);
                    s16x8 f = *(const s16x8*)(ldsX + lr * 2048 + bo);
                    ac[u] = __builtin_amdgcn_mfma_f32_16x16x32_bf16(f, wx[kc + u], ac[u], 0, 0, 0);
                }
            }
        }

        // ---- gate B: own-layer h_{t-1} ----
        if (t > 0) {
            if (tid < 64) gate_wave(flgOwn, l, (uint)t);
        }
        __syncthreads();
        __builtin_amdgcn_fence(__ATOMIC_ACQUIRE, "agent");

        const ushort* hsrc = (t == 0) ? hinit
                           : (layer ? (hdb1 + ((t - 1) & 1) * 65536 + g * 16 * 1024)
                                    : (cbuf + ((t - 1) * 64 + g * 16) * 1024));
#pragma unroll
        for (int i = 0; i < 8; i++) {
            int off = tid * 16 + i * 4096;
            u32x4 v = *(const u32x4*)((const char*)hsrc + off);
            int row = off >> 11;
            int sw = (off & 2047) ^ ((row & 7) << 4);
            *(u32x4*)(ldsH + row * 2048 + sw) = v;
        }
        __syncthreads();

#pragma unroll
        for (int kc = 0; kc < 32; kc += 4) {
#pragma unroll
            for (int u = 0; u < 4; u++) {
                int bo = ((kc + u) * 64 + lq * 16) ^ ((lr & 7) << 4);
                s16x8 f = *(const s16x8*)(ldsH + lr * 2048 + bo);
                ac[u] = __builtin_amdgcn_mfma_f32_16x16x32_bf16(f, wh[kc + u], ac[u], 0, 0, 0);
            }
        }

        float hn[4];
#pragma unroll
        for (int j = 0; j < 4; j++) {
            float z = ac[0][j] + ac[1][j] + ac[2][j] + ac[3][j]
                    + (layer ? bb : bf2f(cf[j]));
            z = fminf(fmaxf(z, -15.f), 15.f);
            float e = __expf(2.f * z);
            hn[j] = (e - 1.f) / (e + 1.f);
        }

        // ---- publish ----
        if (!layer) {
#pragma unroll
            for (int j = 0; j < 4; j++)
                cbuf[cbase + (lq * 4 + j) * 1024 + mycol] = f2bf(hn[j]);
        } else {
            ushort* hdst = hdb1 + (t & 1) * 65536 + g * 16 * 1024;
#pragma unroll
            for (int j = 0; j < 4; j++)
                hdst[(lq * 4 + j) * 1024 + mycol] = f2bf(hn[j]);
            float s = hn[0] + hn[1] + hn[2] + hn[3];
            s += __shfl_xor(s, 16);
            s += __shfl_xor(s, 32);
            if (l < 16) ppart[(g * 1024 + t) * 1024 + mycol] = s;
        }

        __syncthreads();  // each wave: vmcnt(0) before barrier => stores in L2
        if (tid == 0) {
            __builtin_amdgcn_fence(__ATOMIC_RELEASE, "agent");
            __hip_atomic_store(flgOwn + slice, (uint)(t + 1), __ATOMIC_RELAXED,
                               __HIP_MEMORY_SCOPE_AGENT);
        }
    }
}

// ---------------- head: pooled mean -> FC1+ReLU -> FC2+sigmoid ----------------
__launch_bounds__(256)
__global__ void k_head(const float* __restrict__ W1, const float* __restrict__ b1,
                       const float* __restrict__ W2, const float* __restrict__ b2,
                       char* ws, float* __restrict__ out) {
    const float* pp = (const float*)(ws + OFF_PPART);
    int bx = blockIdx.x;
    int t0 = bx * 8;
    int tid = threadIdx.x;

    __shared__ float pl[8][1024];
    __shared__ float red[256][8];

    for (int i = tid; i < 8192; i += 256) {
        int tt = i >> 10, k = i & 1023;
        int base = (t0 + tt) * 1024 + k;
        float s = pp[base] + pp[1048576 + base] + pp[2097152 + base] + pp[3145728 + base];
        pl[tt][k] = s * (1.f / 64.f);
    }
    __syncthreads();

    float po[8];
#pragma unroll
    for (int tt = 0; tt < 8; tt++) po[tt] = 0.f;

    for (int jj = 0; jj < 2; jj++) {
        int j = tid + jj * 256;
        float accv[8];
        float bias = b1[j];
#pragma unroll
        for (int tt = 0; tt < 8; tt++) accv[tt] = bias;
        const float* wr = W1 + (long long)j * 1024;
        for (int k = 0; k < 1024; k += 8) {
            f32x4 wa = *(const f32x4*)(wr + k);
            f32x4 wb = *(const f32x4*)(wr + k + 4);
#pragma unroll
            for (int tt = 0; tt < 8; tt++) {
                accv[tt] += pl[tt][k] * wa[0] + pl[tt][k + 1] * wa[1] +
                            pl[tt][k + 2] * wa[2] + pl[tt][k + 3] * wa[3] +
                            pl[tt][k + 4] * wb[0] + pl[tt][k + 5] * wb[1] +
                            pl[tt][k + 6] * wb[2] + pl[tt][k + 7] * wb[3];
            }
        }
        float w2 = W2[j];
#pragma unroll
        for (int tt = 0; tt < 8; tt++) po[tt] += fmaxf(accv[tt], 0.f) * w2;
    }

#pragma unroll
    for (int tt = 0; tt < 8; tt++) red[tid][tt] = po[tt];
    __syncthreads();
    for (int st = 128; st >= 1; st >>= 1) {
        if (tid < st) {
#pragma unroll
            for (int tt = 0; tt < 8; tt++) red[tid][tt] += red[tid + st][tt];
        }
        __syncthreads();
    }
    if (tid < 8) out[t0 + tid] = 1.f / (1.f + __expf(-(red[0][tid] + b2[0])));
}

extern "C" void kernel_launch(void* const* d_in, const int* in_sizes, int n_in,
                              void* d_out, int out_size, void* d_ws, size_t ws_size,
                              hipStream_t stream) {
    const float* x    = (const float*)d_in[0];
    const float* hid  = (const float*)d_in[1];
    const float* Wih0 = (const float*)d_in[2];
    const float* Whh0 = (const float*)d_in[3];
    const float* bih0 = (const float*)d_in[4];
    const float* bhh0 = (const float*)d_in[5];
    const float* Wih1 = (const float*)d_in[6];
    const float* Whh1 = (const float*)d_in[7];
    const float* bih1 = (const float*)d_in[8];
    const float* bhh1 = (const float*)d_in[9];
    const float* W1   = (const float*)d_in[10];
    const float* b1   = (const float*)d_in[11];
    const float* W2   = (const float*)d_in[12];
    const float* b2   = (const float*)d_in[13];
    char* ws = (char*)d_ws;
    float* out = (float*)d_out;

    hipLaunchKernelGGL(k_prep, dim3(1024), dim3(256), 0, stream,
                       Wih0, Whh0, Wih1, Whh1, hid, ws);
    hipLaunchKernelGGL(k_proj0, dim3(4096), dim3(256), 0, stream, x, bih0, bhh0, ws);
    hipLaunchKernelGGL(k_recf, dim3(128), dim3(256), 0, stream,
                       (const ushort*)(ws + OFF_WH0B), (const ushort*)(ws + OFF_WH1B),
                       (const ushort*)(ws + OFF_W1B),
                       (ushort*)(ws + OFF_BUF), (ushort*)(ws + OFF_HDB1),
                       (const ushort*)(ws + OFF_HINIT), (uint*)(ws + OFF_FLG),
                       (float*)(ws + OFF_PPART), bih1, bhh1);
    hipLaunchKernelGGL(k_head, dim3(128), dim3(256), 0, stream, W1, b1, W2, b2, ws, out);
}

// Round 5
// 13718.874 us; speedup vs baseline: 1.8534x; 1.1114x over previous
//
#include <hip/hip_runtime.h>

typedef unsigned int uint;
typedef unsigned short ushort;
typedef __attribute__((ext_vector_type(8))) short s16x8;
typedef __attribute__((ext_vector_type(4))) float f32x4;
typedef __attribute__((ext_vector_type(4))) uint u32x4;

// problem dims (fixed)
#define SEQ 1024
#define BATCH 64
#define INDIM 512
#define HID 1024

// ---- workspace layout (bytes) ----
#define OFF_BUF   0ull
#define SZ_BUF    (65536ull * 1024ull * 2ull)           // c0 -> r0 (in-place), bf16
#define OFF_W0B   (OFF_BUF + SZ_BUF)                    // W_ih0 bf16 (1024x512)
#define OFF_WH0B  (OFF_W0B  + 1048576ull)               // W_hh0 bf16 (1024x1024)
#define OFF_W1B   (OFF_WH0B + 2097152ull)               // W_ih1 bf16
#define OFF_WH1B  (OFF_W1B  + 2097152ull)               // W_hh1 bf16
#define OFF_HINIT (OFF_WH1B + 2097152ull)               // hidden bf16 [2][64][1024]
#define OFF_HDB1  (OFF_HINIT + 262144ull)               // L1 h double buffer [2][64][1024] bf16
#define OFF_FLG   (OFF_HDB1 + 262144ull)                // flags [2][4][16] x 128B-padded u32
#define OFF_PPART (OFF_FLG + 131072ull)                 // pooled partials [4][1024][1024] f32
#define WS_NEEDED (OFF_PPART + 16777216ull)

__device__ __forceinline__ ushort f2bf(float f) {
    uint u = __float_as_uint(f);
    uint r = (u + 0x7fffu + ((u >> 16) & 1u)) >> 16;
    return (ushort)r;
}
__device__ __forceinline__ float bf2f(ushort h) {
    return __uint_as_float(((uint)h) << 16);
}

// wave0 gate: lanes 0..15 poll padded slots base[l*32] until >= tgt (monotone),
// then lane 0 issues one acquire load (R2-proven pattern).
__device__ __forceinline__ void gate_wave(const uint* base, int l, uint tgt) {
    const uint* fp = (l < 16) ? base + l * 32 : nullptr;
    uint mytgt = (l < 16) ? tgt : 0u;
    for (;;) {
        uint v = fp ? __hip_atomic_load(fp, __ATOMIC_RELAXED, __HIP_MEMORY_SCOPE_AGENT) : 0u;
        if (__all(v >= mytgt)) break;
        __builtin_amdgcn_s_sleep(1);
    }
    if (l == 0)
        (void)__hip_atomic_load(base, __ATOMIC_ACQUIRE, __HIP_MEMORY_SCOPE_AGENT);
}

// ---------------- prep: convert weights/hidden to bf16, zero flags ----------------
__global__ void k_prep(const float* Wih0, const float* Whh0, const float* Wih1,
                       const float* Whh1, const float* hid, char* ws) {
    ushort* w0  = (ushort*)(ws + OFF_W0B);
    ushort* wh0 = (ushort*)(ws + OFF_WH0B);
    ushort* w1  = (ushort*)(ws + OFF_W1B);
    ushort* wh1 = (ushort*)(ws + OFF_WH1B);
    ushort* hi  = (ushort*)(ws + OFF_HINIT);
    uint*   flg = (uint*)(ws + OFF_FLG);
    const long long total = 524288 + 3 * 1048576 + 131072 + 32768;
    for (long long i = (long long)blockIdx.x * 256 + threadIdx.x; i < total;
         i += (long long)gridDim.x * 256) {
        long long j = i;
        if (j < 524288)  { w0[j]  = f2bf(Wih0[j]); continue; }  j -= 524288;
        if (j < 1048576) { wh0[j] = f2bf(Whh0[j]); continue; }  j -= 1048576;
        if (j < 1048576) { w1[j]  = f2bf(Wih1[j]); continue; }  j -= 1048576;
        if (j < 1048576) { wh1[j] = f2bf(Whh1[j]); continue; }  j -= 1048576;
        if (j < 131072)  { hi[j]  = f2bf(hid[j]);  continue; }  j -= 131072;
        flg[j] = 0u;
    }
}

// ---------------- proj0: c0 = x @ W_ih0^T + b_ih0 + b_hh0 (bf16 out) ----------------
__launch_bounds__(256)
__global__ void k_proj0(const float* __restrict__ x, const float* __restrict__ bih,
                        const float* __restrict__ bhh, char* ws) {
    const ushort* W = (const ushort*)(ws + OFF_W0B);
    ushort* cbuf = (ushort*)(ws + OFF_BUF);
    int bx = blockIdx.x;
    int mtile = bx >> 2, ntile = bx & 3;
    int tid = threadIdx.x, w = tid >> 6, l = tid & 63;
    int lr = l & 15, lq = l >> 4;
    int arow = mtile * 64 + w * 16 + lr;

    f32x4 acc[16];
#pragma unroll
    for (int i = 0; i < 16; i++) acc[i] = (f32x4){0.f, 0.f, 0.f, 0.f};

    for (int kc = 0; kc < 16; kc++) {
        int k0 = kc * 32 + lq * 8;
        const f32x4* ap = (const f32x4*)(x + (long long)arow * 512 + k0);
        f32x4 a0 = ap[0], a1 = ap[1];
        s16x8 a;
        a[0] = (short)f2bf(a0[0]); a[1] = (short)f2bf(a0[1]);
        a[2] = (short)f2bf(a0[2]); a[3] = (short)f2bf(a0[3]);
        a[4] = (short)f2bf(a1[0]); a[5] = (short)f2bf(a1[1]);
        a[6] = (short)f2bf(a1[2]); a[7] = (short)f2bf(a1[3]);
#pragma unroll
        for (int nf = 0; nf < 16; nf++) {
            int col = ntile * 256 + nf * 16 + lr;
            s16x8 b = *(const s16x8*)(W + (long long)col * 512 + k0);
            acc[nf] = __builtin_amdgcn_mfma_f32_16x16x32_bf16(a, b, acc[nf], 0, 0, 0);
        }
    }
#pragma unroll
    for (int nf = 0; nf < 16; nf++) {
        int col = ntile * 256 + nf * 16 + lr;
        float bb = bih[col] + bhh[col];
#pragma unroll
        for (int j = 0; j < 4; j++) {
            int row = mtile * 64 + w * 16 + lq * 4 + j;
            cbuf[(long long)row * 1024 + col] = f2bf(acc[nf][j] + bb);
        }
    }
}

// ---------------- fused recurrence (both layers, pipelined) ----------------
// grid 256 x 256.  g = wgid&7 (exit if >=4) => L0-g and L1-g co-resident on XCD g
// under round-robin dispatch.  layer = (wgid>>3)&1, slice = wgid>>4 (16 x 64 cols).
// Weights pinned in VGPRs via opaque asm.  Padded per-producer flags (128B).
// L0: h_t = tanh(c0[t] + h @ Whh0^T); r0 published in place over c0.
// L1: h_t = tanh(r0[t] @ Wih1^T + b + h @ Whh1^T); pooled sums to ppart.
__launch_bounds__(256, 1)
__global__ void k_recf(const ushort* __restrict__ wh0p, const ushort* __restrict__ wh1p,
                       const ushort* __restrict__ wxp,
                       ushort* __restrict__ cbuf, ushort* __restrict__ hdb1,
                       const ushort* __restrict__ hinitb, uint* __restrict__ flg,
                       float* __restrict__ ppart,
                       const float* __restrict__ bih1, const float* __restrict__ bhh1) {
    int wgid = blockIdx.x;
    int g = wgid & 7;
    if (g >= 4) return;
    int layer = (wgid >> 3) & 1;
    int slice = wgid >> 4;
    int tid = threadIdx.x;
    int l = tid & 63, wv = tid >> 6, lr = l & 15, lq = l >> 4;
    int mycol = slice * 64 + wv * 16 + lr;

    const ushort* WhhB = layer ? wh1p : wh0p;
    uint* flgOwn = flg + (layer * 4 + g) * 16 * 32;   // padded: 128B per producer slot
    uint* flgDep = flg + g * 16 * 32;                 // L0 flags (L1's r0 dependency)
    const ushort* hinit = hinitb + layer * 65536 + g * 16 * 1024;

    __shared__ __align__(16) char lds[65536];
    char* ldsH = lds;
    char* ldsX = lds + 32768;

    // register-resident weights (128 VGPR each set), pinned via opaque asm
    s16x8 wh[32], wx[32];
#pragma unroll
    for (int kc = 0; kc < 32; kc++)
        wh[kc] = *(const s16x8*)(WhhB + (long long)mycol * 1024 + kc * 32 + lq * 8);
#pragma unroll
    for (int kc = 0; kc < 32; kc++) asm volatile("" : "+v"(wh[kc]));
    if (layer) {
#pragma unroll
        for (int kc = 0; kc < 32; kc++)
            wx[kc] = *(const s16x8*)(wxp + (long long)mycol * 1024 + kc * 32 + lq * 8);
#pragma unroll
        for (int kc = 0; kc < 32; kc++) asm volatile("" : "+v"(wx[kc]));
    }
    float bb = layer ? (bih1[mycol] + bhh1[mycol]) : 0.f;

    for (int t = 0; t < 1024; t++) {
        int cbase = (t * 64 + g * 16) * 1024;

        f32x4 ac[4];
#pragma unroll
        for (int u = 0; u < 4; u++) ac[u] = (f32x4){0.f, 0.f, 0.f, 0.f};

        ushort cf[4];
        if (!layer) {
            // prefetch own-col c0[t] (independent of recurrence) before gating
#pragma unroll
            for (int j = 0; j < 4; j++)
                cf[j] = cbuf[cbase + (lq * 4 + j) * 1024 + mycol];
        } else {
            // ---- gate A: r0[t] published by L0 group g ----
            if (tid < 64) gate_wave(flgDep, l, (uint)(t + 1));
            __syncthreads();
            const ushort* xsrc = cbuf + cbase;
#pragma unroll
            for (int i = 0; i < 8; i++) {
                int off = tid * 16 + i * 4096;
                u32x4 v = *(const u32x4*)((const char*)xsrc + off);
                int row = off >> 11;
                int sw = (off & 2047) ^ ((row & 7) << 4);
                *(u32x4*)(ldsX + row * 2048 + sw) = v;
            }
            __syncthreads();
            // Wih1 GEMM overlaps the wait for h1[t-1]
#pragma unroll
            for (int kc = 0; kc < 32; kc += 4) {
#pragma unroll
                for (int u = 0; u < 4; u++) {
                    int bo = ((kc + u) * 64 + lq * 16) ^ ((lr & 7) << 4);
                    s16x8 f = *(const s16x8*)(ldsX + lr * 2048 + bo);
                    ac[u] = __builtin_amdgcn_mfma_f32_16x16x32_bf16(f, wx[kc + u], ac[u], 0, 0, 0);
                }
            }
        }

        // ---- gate B: own-layer h_{t-1} ----
        if (t > 0) {
            if (tid < 64) gate_wave(flgOwn, l, (uint)t);
        }
        __syncthreads();

        const ushort* hsrc = (t == 0) ? hinit
                           : (layer ? (hdb1 + ((t - 1) & 1) * 65536 + g * 16 * 1024)
                                    : (cbuf + ((t - 1) * 64 + g * 16) * 1024));
#pragma unroll
        for (int i = 0; i < 8; i++) {
            int off = tid * 16 + i * 4096;
            u32x4 v = *(const u32x4*)((const char*)hsrc + off);
            int row = off >> 11;
            int sw = (off & 2047) ^ ((row & 7) << 4);
            *(u32x4*)(ldsH + row * 2048 + sw) = v;
        }
        __syncthreads();

#pragma unroll
        for (int kc = 0; kc < 32; kc += 4) {
#pragma unroll
            for (int u = 0; u < 4; u++) {
                int bo = ((kc + u) * 64 + lq * 16) ^ ((lr & 7) << 4);
                s16x8 f = *(const s16x8*)(ldsH + lr * 2048 + bo);
                ac[u] = __builtin_amdgcn_mfma_f32_16x16x32_bf16(f, wh[kc + u], ac[u], 0, 0, 0);
            }
        }

        float hn[4];
#pragma unroll
        for (int j = 0; j < 4; j++) {
            float z = ac[0][j] + ac[1][j] + ac[2][j] + ac[3][j]
                    + (layer ? bb : bf2f(cf[j]));
            z = fminf(fmaxf(z, -15.f), 15.f);
            float e = __expf(2.f * z);
            hn[j] = (e - 1.f) / (e + 1.f);
        }

        // ---- publish ----
        if (!layer) {
#pragma unroll
            for (int j = 0; j < 4; j++)
                cbuf[cbase + (lq * 4 + j) * 1024 + mycol] = f2bf(hn[j]);
        } else {
            ushort* hdst = hdb1 + (t & 1) * 65536 + g * 16 * 1024;
#pragma unroll
            for (int j = 0; j < 4; j++)
                hdst[(lq * 4 + j) * 1024 + mycol] = f2bf(hn[j]);
            float s = hn[0] + hn[1] + hn[2] + hn[3];
            s += __shfl_xor(s, 16);
            s += __shfl_xor(s, 32);
            if (l < 16) ppart[(g * 1024 + t) * 1024 + mycol] = s;
        }

        __syncthreads();  // each wave: vmcnt(0) before barrier => stores complete
        if (tid == 0)
            __hip_atomic_store(flgOwn + slice * 32, (uint)(t + 1), __ATOMIC_RELEASE,
                               __HIP_MEMORY_SCOPE_AGENT);
    }
}

// ---------------- head: pooled mean -> FC1+ReLU -> FC2+sigmoid ----------------
__launch_bounds__(256)
__global__ void k_head(const float* __restrict__ W1, const float* __restrict__ b1,
                       const float* __restrict__ W2, const float* __restrict__ b2,
                       char* ws, float* __restrict__ out) {
    const float* pp = (const float*)(ws + OFF_PPART);
    int bx = blockIdx.x;
    int t0 = bx * 8;
    int tid = threadIdx.x;

    __shared__ float pl[8][1024];
    __shared__ float red[256][8];

    for (int i = tid; i < 8192; i += 256) {
        int tt = i >> 10, k = i & 1023;
        int base = (t0 + tt) * 1024 + k;
        float s = pp[base] + pp[1048576 + base] + pp[2097152 + base] + pp[3145728 + base];
        pl[tt][k] = s * (1.f / 64.f);
    }
    __syncthreads();

    float po[8];
#pragma unroll
    for (int tt = 0; tt < 8; tt++) po[tt] = 0.f;

    for (int jj = 0; jj < 2; jj++) {
        int j = tid + jj * 256;
        float accv[8];
        float bias = b1[j];
#pragma unroll
        for (int tt = 0; tt < 8; tt++) accv[tt] = bias;
        const float* wr = W1 + (long long)j * 1024;
        for (int k = 0; k < 1024; k += 8) {
            f32x4 wa = *(const f32x4*)(wr + k);
            f32x4 wb = *(const f32x4*)(wr + k + 4);
#pragma unroll
            for (int tt = 0; tt < 8; tt++) {
                accv[tt] += pl[tt][k] * wa[0] + pl[tt][k + 1] * wa[1] +
                            pl[tt][k + 2] * wa[2] + pl[tt][k + 3] * wa[3] +
                            pl[tt][k + 4] * wb[0] + pl[tt][k + 5] * wb[1] +
                            pl[tt][k + 6] * wb[2] + pl[tt][k + 7] * wb[3];
            }
        }
        float w2 = W2[j];
#pragma unroll
        for (int tt = 0; tt < 8; tt++) po[tt] += fmaxf(accv[tt], 0.f) * w2;
    }

#pragma unroll
    for (int tt = 0; tt < 8; tt++) red[tid][tt] = po[tt];
    __syncthreads();
    for (int st = 128; st >= 1; st >>= 1) {
        if (tid < st) {
#pragma unroll
            for (int tt = 0; tt < 8; tt++) red[tid][tt] += red[tid + st][tt];
        }
        __syncthreads();
    }
    if (tid < 8) out[t0 + tid] = 1.f / (1.f + __expf(-(red[0][tid] + b2[0])));
}

extern "C" void kernel_launch(void* const* d_in, const int* in_sizes, int n_in,
                              void* d_out, int out_size, void* d_ws, size_t ws_size,
                              hipStream_t stream) {
    const float* x    = (const float*)d_in[0];
    const float* hid  = (const float*)d_in[1];
    const float* Wih0 = (const float*)d_in[2];
    const float* Whh0 = (const float*)d_in[3];
    const float* bih0 = (const float*)d_in[4];
    const float* bhh0 = (const float*)d_in[5];
    const float* Wih1 = (const float*)d_in[6];
    const float* Whh1 = (const float*)d_in[7];
    const float* bih1 = (const float*)d_in[8];
    const float* bhh1 = (const float*)d_in[9];
    const float* W1   = (const float*)d_in[10];
    const float* b1   = (const float*)d_in[11];
    const float* W2   = (const float*)d_in[12];
    const float* b2   = (const float*)d_in[13];
    char* ws = (char*)d_ws;
    float* out = (float*)d_out;

    hipLaunchKernelGGL(k_prep, dim3(1024), dim3(256), 0, stream,
                       Wih0, Whh0, Wih1, Whh1, hid, ws);
    hipLaunchKernelGGL(k_proj0, dim3(4096), dim3(256), 0, stream, x, bih0, bhh0, ws);
    hipLaunchKernelGGL(k_recf, dim3(256), dim3(256), 0, stream,
                       (const ushort*)(ws + OFF_WH0B), (const ushort*)(ws + OFF_WH1B),
                       (const ushort*)(ws + OFF_W1B),
                       (ushort*)(ws + OFF_BUF), (ushort*)(ws + OFF_HDB1),
                       (const ushort*)(ws + OFF_HINIT), (uint*)(ws + OFF_FLG),
                       (float*)(ws + OFF_PPART), bih1, bhh1);
    hipLaunchKernelGGL(k_head, dim3(128), dim3(256), 0, stream, W1, b1, W2, b2, ws, out);
}

// Round 8
// 8733.469 us; speedup vs baseline: 2.9114x; 1.5708x over previous
//
#include <hip/hip_runtime.h>

typedef unsigned int uint;
typedef unsigned short ushort;
typedef unsigned long long u64;
typedef __attribute__((ext_vector_type(8))) short s16x8;
typedef __attribute__((ext_vector_type(4))) float f32x4;
typedef __attribute__((ext_vector_type(4))) uint u32x4;

// problem dims (fixed)
#define SEQ 1024
#define BATCH 64
#define INDIM 512
#define HID 1024

// ---- workspace layout (bytes) ----
#define OFF_BUF   0ull
#define SZ_BUF    (65536ull * 1024ull * 2ull)           // c0 -> r0 (in-place), bf16
#define OFF_W0B   (OFF_BUF + SZ_BUF)                    // W_ih0 bf16 (1024x512)
#define OFF_WH0B  (OFF_W0B  + 1048576ull)               // W_hh0 bf16
#define OFF_W1B   (OFF_WH0B + 2097152ull)               // W_ih1 bf16
#define OFF_WH1B  (OFF_W1B  + 2097152ull)               // W_hh1 bf16
#define OFF_HINIT (OFF_WH1B + 2097152ull)               // hidden bf16 [2][64][1024]
#define OFF_HDB1  (OFF_HINIT + 262144ull)               // L1 h double buffer [2][64][1024]
#define OFF_FLG   (OFF_HDB1 + 262144ull)                // 3 flag sets, 128B-padded slots
#define OFF_RING  (OFF_FLG + 131072ull)                 // c1 ring [64][8][16][64] f32 = 2MB
#define OFF_PPART (OFF_RING + 2097152ull)               // pooled partials [4][1024][1024] f32
#define WS_NEEDED (OFF_PPART + 16777216ull)

__device__ __forceinline__ ushort f2bf(float f) {
    uint u = __float_as_uint(f);
    uint r = (u + 0x7fffu + ((u >> 16) & 1u)) >> 16;
    return (ushort)r;
}
__device__ __forceinline__ float bf2f(ushort h) {
    return __uint_as_float(((uint)h) << 16);
}

// R2/R5-proven gate: lanes 0-15 poll A-slots (128B padded) >= tA; lanes 16-31
// poll B (bstrideWords between slots; 0 = single slot) >= tB.  After success,
// lane 0 issues ONE acquire load (buffer_inv) covering both datasets.
__device__ __forceinline__ void gate2(const uint* A, uint tA,
                                      const uint* B, uint tB, int bstrideWords, int l) {
    const uint* fp; uint tgt;
    if (l < 16) { fp = A + l * 32; tgt = tA; }
    else if (l < 32 && B) { fp = B + (l - 16) * bstrideWords; tgt = tB; }
    else { fp = A; tgt = 0u; }
    for (;;) {
        uint v = __hip_atomic_load(fp, __ATOMIC_RELAXED, __HIP_MEMORY_SCOPE_AGENT);
        if (__all(v >= tgt)) break;
        __builtin_amdgcn_s_sleep(1);
    }
    if (l == 0)
        (void)__hip_atomic_load(A, __ATOMIC_ACQUIRE, __HIP_MEMORY_SCOPE_AGENT);
}

// ---------------- prep: convert weights/hidden to bf16, zero flags ----------------
__global__ void k_prep(const float* Wih0, const float* Whh0, const float* Wih1,
                       const float* Whh1, const float* hid, char* ws) {
    ushort* w0  = (ushort*)(ws + OFF_W0B);
    ushort* wh0 = (ushort*)(ws + OFF_WH0B);
    ushort* w1  = (ushort*)(ws + OFF_W1B);
    ushort* wh1 = (ushort*)(ws + OFF_WH1B);
    ushort* hi  = (ushort*)(ws + OFF_HINIT);
    uint*   flg = (uint*)(ws + OFF_FLG);
    const long long total = 524288 + 3 * 1048576 + 131072 + 32768;
    for (long long i = (long long)blockIdx.x * 256 + threadIdx.x; i < total;
         i += (long long)gridDim.x * 256) {
        long long j = i;
        if (j < 524288)  { w0[j]  = f2bf(Wih0[j]); continue; }  j -= 524288;
        if (j < 1048576) { wh0[j] = f2bf(Whh0[j]); continue; }  j -= 1048576;
        if (j < 1048576) { w1[j]  = f2bf(Wih1[j]); continue; }  j -= 1048576;
        if (j < 1048576) { wh1[j] = f2bf(Whh1[j]); continue; }  j -= 1048576;
        if (j < 131072)  { hi[j]  = f2bf(hid[j]);  continue; }  j -= 131072;
        flg[j] = 0u;
    }
}

// ---------------- proj0: c0 = x @ W_ih0^T + b_ih0 + b_hh0 (bf16 out) ----------------
__launch_bounds__(256)
__global__ void k_proj0(const float* __restrict__ x, const float* __restrict__ bih,
                        const float* __restrict__ bhh, char* ws) {
    const ushort* W = (const ushort*)(ws + OFF_W0B);
    ushort* cbuf = (ushort*)(ws + OFF_BUF);
    int bx = blockIdx.x;
    int mtile = bx >> 2, ntile = bx & 3;
    int tid = threadIdx.x, w = tid >> 6, l = tid & 63;
    int lr = l & 15, lq = l >> 4;
    int arow = mtile * 64 + w * 16 + lr;

    f32x4 acc[16];
#pragma unroll
    for (int i = 0; i < 16; i++) acc[i] = (f32x4){0.f, 0.f, 0.f, 0.f};

    for (int kc = 0; kc < 16; kc++) {
        int k0 = kc * 32 + lq * 8;
        const f32x4* ap = (const f32x4*)(x + (long long)arow * 512 + k0);
        f32x4 a0 = ap[0], a1 = ap[1];
        s16x8 a;
        a[0] = (short)f2bf(a0[0]); a[1] = (short)f2bf(a0[1]);
        a[2] = (short)f2bf(a0[2]); a[3] = (short)f2bf(a0[3]);
        a[4] = (short)f2bf(a1[0]); a[5] = (short)f2bf(a1[1]);
        a[6] = (short)f2bf(a1[2]); a[7] = (short)f2bf(a1[3]);
#pragma unroll
        for (int nf = 0; nf < 16; nf++) {
            int col = ntile * 256 + nf * 16 + lr;
            s16x8 b = *(const s16x8*)(W + (long long)col * 512 + k0);
            acc[nf] = __builtin_amdgcn_mfma_f32_16x16x32_bf16(a, b, acc[nf], 0, 0, 0);
        }
    }
#pragma unroll
    for (int nf = 0; nf < 16; nf++) {
        int col = ntile * 256 + nf * 16 + lr;
        float bb = bih[col] + bhh[col];
#pragma unroll
        for (int j = 0; j < 4; j++) {
            int row = mtile * 64 + w * 16 + lq * 4 + j;
            cbuf[(long long)row * 1024 + col] = f2bf(acc[nf][j] + bb);
        }
    }
}

// ---------------- fused pipeline: L0-rec | proj1-stream | L1-rec ----------------
// grid 192 x 256.  role = wgid>>6 (0:L0, 1:proj1, 2:L1); sub = wgid&63;
// g = sub&3 (batch group of 16 rows), s = sub>>2 (64 hidden cols).
// Handshake (R2/R5-proven): producers publish with PLAIN stores ->
// __syncthreads (vmcnt drain) -> lane-0 RELEASE store to padded slot;
// consumers poll relaxed -> lane-0 ACQUIRE load -> __syncthreads -> PLAIN loads.
// Zero spill: exactly one 128-VGPR weight set per WG.
__launch_bounds__(256, 1)
__global__ void k_recf(const ushort* __restrict__ wh0p, const ushort* __restrict__ wh1p,
                       const ushort* __restrict__ wxp,
                       ushort* __restrict__ cbuf, ushort* __restrict__ hdb1,
                       const ushort* __restrict__ hinitb, uint* __restrict__ flg,
                       float* __restrict__ ring, float* __restrict__ ppart,
                       const float* __restrict__ bih1, const float* __restrict__ bhh1) {
    int wgid = blockIdx.x;
    int role = wgid >> 6;
    int sub = wgid & 63;
    int g = sub & 3, s = sub >> 2;
    int tid = threadIdx.x;
    int l = tid & 63, wv = tid >> 6, lr = l & 15, lq = l >> 4;
    int mycol = s * 64 + wv * 16 + lr;

    uint* f0 = flg;                 // [4][16] slots * 32 u32 stride (128B padded)
    uint* fc = flg + 2048;
    uint* f1 = flg + 4096;

    const ushort* Wp = (role == 0) ? wh0p : (role == 1) ? wxp : wh1p;
    uint* myslot = ((role == 0) ? f0 : (role == 1) ? fc : f1) + (g * 16 + s) * 32;

    __shared__ __align__(16) char lds[32768];

    // register-resident weight slice (128 VGPR), pinned
    s16x8 wgt[32];
#pragma unroll
    for (int kc = 0; kc < 32; kc++)
        wgt[kc] = *(const s16x8*)(Wp + (long long)mycol * 1024 + kc * 32 + lq * 8);
#pragma unroll
    for (int kc = 0; kc < 32; kc++) asm volatile("" : "+v"(wgt[kc]));

    float bb = (role == 1) ? (bih1[mycol] + bhh1[mycol]) : 0.f;
    // ring slice base for this (g,s): [slice][8 slots][16 rows][64 cols] f32
    float* ringMy = ring + (long long)(g * 16 + s) * 8 * 16 * 64;

    for (int t = 0; t < 1024; t++) {
        int cbase = (t * 64 + g * 16) * 1024;

        ushort cf[4];
        if (role == 0) {
            // prefetch own-col c0[t] (proj0 output, stable; own cols only)
#pragma unroll
            for (int j = 0; j < 4; j++)
                cf[j] = cbuf[cbase + (lq * 4 + j) * 1024 + mycol];
        }

        // ---- gate (wave 0 polls; lane 0 acquires) ----
        if (tid < 64) {
            if (role == 0)      gate2(f0 + g * 16 * 32, (uint)t, nullptr, 0u, 0, l);
            else if (role == 1) gate2(f0 + g * 16 * 32, (uint)(t + 1),
                                      f1 + g * 16 * 32, (t >= 8) ? (uint)(t - 7) : 0u, 32, l);
            else                gate2(f1 + g * 16 * 32, (uint)t,
                                      fc + (g * 16 + s) * 32, (uint)(t + 1), 0, l);
        }
        __syncthreads();

        // ---- c1 ring loads (role 2): plain f32, after acquire ----
        float c1f[4] = {0.f, 0.f, 0.f, 0.f};
        if (role == 2) {
            const float* rs = ringMy + (long long)(t & 7) * 16 * 64 + (wv * 16 + lr);
#pragma unroll
            for (int j = 0; j < 4; j++) c1f[j] = rs[(lq * 4 + j) * 64];
        }

        // ---- stage A-tile (16 x 1024 bf16 = 32KB) via PLAIN loads ----
        const char* src;
        if (role == 0)
            src = (const char*)((t == 0) ? (hinitb + g * 16 * 1024)
                                         : (cbuf + ((t - 1) * 64 + g * 16) * 1024));
        else if (role == 1)
            src = (const char*)(cbuf + cbase);
        else
            src = (const char*)((t == 0) ? (hinitb + 65536 + g * 16 * 1024)
                                         : (hdb1 + ((t - 1) & 1) * 65536 + g * 16 * 1024));

#pragma unroll
        for (int i = 0; i < 8; i++) {
            int off = tid * 16 + i * 4096;
            u32x4 v = *(const u32x4*)(src + off);
            int row = off >> 11;
            int sw = (off & 2047) ^ ((row & 7) << 4);
            *(u32x4*)(lds + row * 2048 + sw) = v;
        }
        __syncthreads();

        // ---- GEMM: 32 MFMAs, 4 accumulator chains ----
        f32x4 ac[4];
#pragma unroll
        for (int u = 0; u < 4; u++) ac[u] = (f32x4){0.f, 0.f, 0.f, 0.f};
#pragma unroll
        for (int kc = 0; kc < 32; kc += 4) {
#pragma unroll
            for (int u = 0; u < 4; u++) {
                int bo = ((kc + u) * 64 + lq * 16) ^ ((lr & 7) << 4);
                s16x8 f = *(const s16x8*)(lds + lr * 2048 + bo);
                ac[u] = __builtin_amdgcn_mfma_f32_16x16x32_bf16(f, wgt[kc + u], ac[u], 0, 0, 0);
            }
        }

        float z[4], hn[4];
#pragma unroll
        for (int j = 0; j < 4; j++) z[j] = ac[0][j] + ac[1][j] + ac[2][j] + ac[3][j];

        // ---- publish (PLAIN stores) ----
        if (role == 0) {
#pragma unroll
            for (int j = 0; j < 4; j++) {
                float zz = fminf(fmaxf(z[j] + bf2f(cf[j]), -15.f), 15.f);
                float e = __expf(2.f * zz);
                hn[j] = (e - 1.f) / (e + 1.f);
            }
#pragma unroll
            for (int j = 0; j < 4; j++)
                cbuf[cbase + (lq * 4 + j) * 1024 + mycol] = f2bf(hn[j]);
        } else if (role == 1) {
            float* rd = ringMy + (long long)(t & 7) * 16 * 64 + (wv * 16 + lr);
#pragma unroll
            for (int j = 0; j < 4; j++)
                rd[(lq * 4 + j) * 64] = z[j] + bb;
        } else {
#pragma unroll
            for (int j = 0; j < 4; j++) {
                float zz = fminf(fmaxf(z[j] + c1f[j], -15.f), 15.f);
                float e = __expf(2.f * zz);
                hn[j] = (e - 1.f) / (e + 1.f);
            }
            ushort* hdst = hdb1 + (t & 1) * 65536 + g * 16 * 1024;
#pragma unroll
            for (int j = 0; j < 4; j++)
                hdst[(lq * 4 + j) * 1024 + mycol] = f2bf(hn[j]);
            float sm = hn[0] + hn[1] + hn[2] + hn[3];
            sm += __shfl_xor(sm, 16);
            sm += __shfl_xor(sm, 32);
            if (l < 16) ppart[(g * 1024 + t) * 1024 + mycol] = sm;
        }

        __syncthreads();       // each wave drains vmcnt before barrier
        if (tid == 0)
            __hip_atomic_store(myslot, (uint)(t + 1), __ATOMIC_RELEASE,
                               __HIP_MEMORY_SCOPE_AGENT);
    }
}

// ---------------- head: pooled mean -> FC1+ReLU -> FC2+sigmoid ----------------
__launch_bounds__(256)
__global__ void k_head(const float* __restrict__ W1, const float* __restrict__ b1,
                       const float* __restrict__ W2, const float* __restrict__ b2,
                       char* ws, float* __restrict__ out) {
    const float* pp = (const float*)(ws + OFF_PPART);
    int bx = blockIdx.x;
    int t0 = bx * 8;
    int tid = threadIdx.x;

    __shared__ float pl[8][1024];
    __shared__ float red[256][8];

    for (int i = tid; i < 8192; i += 256) {
        int tt = i >> 10, k = i & 1023;
        int base = (t0 + tt) * 1024 + k;
        float s = pp[base] + pp[1048576 + base] + pp[2097152 + base] + pp[3145728 + base];
        pl[tt][k] = s * (1.f / 64.f);
    }
    __syncthreads();

    float po[8];
#pragma unroll
    for (int tt = 0; tt < 8; tt++) po[tt] = 0.f;

    for (int jj = 0; jj < 2; jj++) {
        int j = tid + jj * 256;
        float accv[8];
        float bias = b1[j];
#pragma unroll
        for (int tt = 0; tt < 8; tt++) accv[tt] = bias;
        const float* wr = W1 + (long long)j * 1024;
        for (int k = 0; k < 1024; k += 8) {
            f32x4 wa = *(const f32x4*)(wr + k);
            f32x4 wb = *(const f32x4*)(wr + k + 4);
#pragma unroll
            for (int tt = 0; tt < 8; tt++) {
                accv[tt] += pl[tt][k] * wa[0] + pl[tt][k + 1] * wa[1] +
                            pl[tt][k + 2] * wa[2] + pl[tt][k + 3] * wa[3] +
                            pl[tt][k + 4] * wb[0] + pl[tt][k + 5] * wb[1] +
                            pl[tt][k + 6] * wb[2] + pl[tt][k + 7] * wb[3];
            }
        }
        float w2 = W2[j];
#pragma unroll
        for (int tt = 0; tt < 8; tt++) po[tt] += fmaxf(accv[tt], 0.f) * w2;
    }

#pragma unroll
    for (int tt = 0; tt < 8; tt++) red[tid][tt] = po[tt];
    __syncthreads();
    for (int st = 128; st >= 1; st >>= 1) {
        if (tid < st) {
#pragma unroll
            for (int tt = 0; tt < 8; tt++) red[tid][tt] += red[tid + st][tt];
        }
        __syncthreads();
    }
    if (tid < 8) out[t0 + tid] = 1.f / (1.f + __expf(-(red[0][tid] + b2[0])));
}

extern "C" void kernel_launch(void* const* d_in, const int* in_sizes, int n_in,
                              void* d_out, int out_size, void* d_ws, size_t ws_size,
                              hipStream_t stream) {
    const float* x    = (const float*)d_in[0];
    const float* hid  = (const float*)d_in[1];
    const float* Wih0 = (const float*)d_in[2];
    const float* Whh0 = (const float*)d_in[3];
    const float* bih0 = (const float*)d_in[4];
    const float* bhh0 = (const float*)d_in[5];
    const float* Wih1 = (const float*)d_in[6];
    const float* Whh1 = (const float*)d_in[7];
    const float* bih1 = (const float*)d_in[8];
    const float* bhh1 = (const float*)d_in[9];
    const float* W1   = (const float*)d_in[10];
    const float* b1   = (const float*)d_in[11];
    const float* W2   = (const float*)d_in[12];
    const float* b2   = (const float*)d_in[13];
    char* ws = (char*)d_ws;
    float* out = (float*)d_out;

    hipLaunchKernelGGL(k_prep, dim3(1024), dim3(256), 0, stream,
                       Wih0, Whh0, Wih1, Whh1, hid, ws);
    hipLaunchKernelGGL(k_proj0, dim3(4096), dim3(256), 0, stream, x, bih0, bhh0, ws);
    hipLaunchKernelGGL(k_recf, dim3(192), dim3(256), 0, stream,
                       (const ushort*)(ws + OFF_WH0B), (const ushort*)(ws + OFF_WH1B),
                       (const ushort*)(ws + OFF_W1B),
                       (ushort*)(ws + OFF_BUF), (ushort*)(ws + OFF_HDB1),
                       (const ushort*)(ws + OFF_HINIT), (uint*)(ws + OFF_FLG),
                       (float*)(ws + OFF_RING), (float*)(ws + OFF_PPART),
                       bih1, bhh1);
    hipLaunchKernelGGL(k_head, dim3(128), dim3(256), 0, stream, W1, b1, W2, b2, ws, out);
}

// Round 9
// 8059.369 us; speedup vs baseline: 3.1549x; 1.0836x over previous
//
#include <hip/hip_runtime.h>

typedef unsigned int uint;
typedef unsigned short ushort;
typedef __attribute__((ext_vector_type(8))) short s16x8;
typedef __attribute__((ext_vector_type(4))) float f32x4;
typedef __attribute__((ext_vector_type(4))) uint u32x4;

// problem dims (fixed)
#define SEQ 1024
#define BATCH 64
#define INDIM 512
#define HID 1024

// ---- workspace layout (bytes) ----
#define OFF_BUF   0ull
#define SZ_BUF    (65536ull * 1024ull * 2ull)           // c0 -> r0 (in-place), bf16
#define OFF_W0B   (OFF_BUF + SZ_BUF)                    // W_ih0 bf16 (1024x512)
#define OFF_WH0B  (OFF_W0B  + 1048576ull)               // W_hh0 bf16
#define OFF_W1B   (OFF_WH0B + 2097152ull)               // W_ih1 bf16
#define OFF_WH1B  (OFF_W1B  + 2097152ull)               // W_hh1 bf16
#define OFF_HINIT (OFF_WH1B + 2097152ull)               // hidden bf16 [2][64][1024]
#define OFF_HDB1  (OFF_HINIT + 262144ull)               // L1 h double buffer [2][64][1024]
#define OFF_FLG   (OFF_HDB1 + 262144ull)                // flag sets, 128B-padded slots
#define OFF_RING  (OFF_FLG + 131072ull)                 // c1 ring [4][16][16][16][64] f32 = 4MB
#define OFF_PPART (OFF_RING + 4194304ull)               // pooled partials [4][1024][1024] f32
#define WS_NEEDED (OFF_PPART + 16777216ull)

__device__ __forceinline__ ushort f2bf(float f) {
    uint u = __float_as_uint(f);
    uint r = (u + 0x7fffu + ((u >> 16) & 1u)) >> 16;
    return (ushort)r;
}
__device__ __forceinline__ float bf2f(ushort h) {
    return __uint_as_float(((uint)h) << 16);
}

// each lane polls its own fp until >= tgt (monotone counters)
__device__ __forceinline__ void poll_all(const uint* fp, uint tgt) {
    for (;;) {
        uint v = __hip_atomic_load(fp, __ATOMIC_RELAXED, __HIP_MEMORY_SCOPE_AGENT);
        if (__all(v >= tgt)) break;
        __builtin_amdgcn_s_sleep(1);
    }
}

// ---------------- prep ----------------
__global__ void k_prep(const float* Wih0, const float* Whh0, const float* Wih1,
                       const float* Whh1, const float* hid, char* ws) {
    ushort* w0  = (ushort*)(ws + OFF_W0B);
    ushort* wh0 = (ushort*)(ws + OFF_WH0B);
    ushort* w1  = (ushort*)(ws + OFF_W1B);
    ushort* wh1 = (ushort*)(ws + OFF_WH1B);
    ushort* hi  = (ushort*)(ws + OFF_HINIT);
    uint*   flg = (uint*)(ws + OFF_FLG);
    const long long total = 524288 + 3 * 1048576 + 131072 + 32768;
    for (long long i = (long long)blockIdx.x * 256 + threadIdx.x; i < total;
         i += (long long)gridDim.x * 256) {
        long long j = i;
        if (j < 524288)  { w0[j]  = f2bf(Wih0[j]); continue; }  j -= 524288;
        if (j < 1048576) { wh0[j] = f2bf(Whh0[j]); continue; }  j -= 1048576;
        if (j < 1048576) { w1[j]  = f2bf(Wih1[j]); continue; }  j -= 1048576;
        if (j < 1048576) { wh1[j] = f2bf(Whh1[j]); continue; }  j -= 1048576;
        if (j < 131072)  { hi[j]  = f2bf(hid[j]);  continue; }  j -= 131072;
        flg[j] = 0u;
    }
}

// ---------------- proj0 ----------------
__launch_bounds__(256)
__global__ void k_proj0(const float* __restrict__ x, const float* __restrict__ bih,
                        const float* __restrict__ bhh, char* ws) {
    const ushort* W = (const ushort*)(ws + OFF_W0B);
    ushort* cbuf = (ushort*)(ws + OFF_BUF);
    int bx = blockIdx.x;
    int mtile = bx >> 2, ntile = bx & 3;
    int tid = threadIdx.x, w = tid >> 6, l = tid & 63;
    int lr = l & 15, lq = l >> 4;
    int arow = mtile * 64 + w * 16 + lr;

    f32x4 acc[16];
#pragma unroll
    for (int i = 0; i < 16; i++) acc[i] = (f32x4){0.f, 0.f, 0.f, 0.f};

    for (int kc = 0; kc < 16; kc++) {
        int k0 = kc * 32 + lq * 8;
        const f32x4* ap = (const f32x4*)(x + (long long)arow * 512 + k0);
        f32x4 a0 = ap[0], a1 = ap[1];
        s16x8 a;
        a[0] = (short)f2bf(a0[0]); a[1] = (short)f2bf(a0[1]);
        a[2] = (short)f2bf(a0[2]); a[3] = (short)f2bf(a0[3]);
        a[4] = (short)f2bf(a1[0]); a[5] = (short)f2bf(a1[1]);
        a[6] = (short)f2bf(a1[2]); a[7] = (short)f2bf(a1[3]);
#pragma unroll
        for (int nf = 0; nf < 16; nf++) {
            int col = ntile * 256 + nf * 16 + lr;
            s16x8 b = *(const s16x8*)(W + (long long)col * 512 + k0);
            acc[nf] = __builtin_amdgcn_mfma_f32_16x16x32_bf16(a, b, acc[nf], 0, 0, 0);
        }
    }
#pragma unroll
    for (int nf = 0; nf < 16; nf++) {
        int col = ntile * 256 + nf * 16 + lr;
        float bb = bih[col] + bhh[col];
#pragma unroll
        for (int j = 0; j < 4; j++) {
            int row = mtile * 64 + w * 16 + lq * 4 + j;
            cbuf[(long long)row * 1024 + col] = f2bf(acc[nf][j] + bb);
        }
    }
}

// ---------------- fused pipeline: L0 | chunked-proj1 | L1 ----------------
// grid 128 x 256.  xcd = wgid&7, hi = wgid>>3.
//  xcd<4 : g=xcd;  hi<8 -> role0 (L0, s=hi);  hi>=8 -> role2 (L1, s=hi-8)
//  xcd>=4: role1 (proj1), g=xcd-4, s=hi (0..15)
// L0/L1: 8 WGs/group, 128 cols each (2 x 16-col fragments/wave, ~256 regs -> AGPR).
// proj1: 16 WGs/group, 64 cols, processes 8 timesteps per sync chunk.
// Handshake (R8-proven): plain stores -> __syncthreads -> lane-0 RELEASE;
// relaxed poll -> lane-0 ACQUIRE -> __syncthreads -> plain loads.
__launch_bounds__(256, 1)
__global__ void k_recf(const ushort* __restrict__ wh0p, const ushort* __restrict__ wh1p,
                       const ushort* __restrict__ wxp,
                       ushort* __restrict__ cbuf, ushort* __restrict__ hdb1,
                       const ushort* __restrict__ hinitb, uint* __restrict__ flg,
                       float* __restrict__ ring, float* __restrict__ ppart,
                       const float* __restrict__ bih1, const float* __restrict__ bhh1) {
    int wgid = blockIdx.x;
    int x = wgid & 7, hi = wgid >> 3;
    int role, g, s;
    if (x < 4) { g = x; if (hi < 8) { role = 0; s = hi; } else { role = 2; s = hi - 8; } }
    else       { role = 1; g = x - 4; s = hi; }

    int tid = threadIdx.x;
    int l = tid & 63, wv = tid >> 6, lr = l & 15, lq = l >> 4;

    uint* f0g = flg + (g * 8) * 32;            // L0 flags: 8 slots/group
    uint* f1g = flg + 1024 + (g * 8) * 32;     // L1 flags: 8 slots/group
    uint* fcg = flg + 2048 + (g * 16) * 32;    // proj1 flags: 16 slots/group

    __shared__ __align__(16) char lds[32768];

    // weight fragments (B-layout: B[k][col] = W[col][k])
    int colA = (role == 1) ? (s * 64 + wv * 16 + lr) : (s * 128 + wv * 16 + lr);
    int colB = (role == 1) ? colA : (s * 128 + 64 + wv * 16 + lr);
    const ushort* Wb = (role == 0) ? wh0p : (role == 1) ? wxp : wh1p;

    s16x8 wgtA[32], wgtB[32];
#pragma unroll
    for (int kc = 0; kc < 32; kc++)
        wgtA[kc] = *(const s16x8*)(Wb + (long long)colA * 1024 + kc * 32 + lq * 8);
#pragma unroll
    for (int kc = 0; kc < 32; kc++) asm volatile("" : "+v"(wgtA[kc]));
    if (role != 1) {
#pragma unroll
        for (int kc = 0; kc < 32; kc++)
            wgtB[kc] = *(const s16x8*)(Wb + (long long)colB * 1024 + kc * 32 + lq * 8);
#pragma unroll
        for (int kc = 0; kc < 32; kc++) asm volatile("" : "+v"(wgtB[kc]));
    }

    if (role == 1) {
        float bb = bih1[colA] + bhh1[colA];
        uint* myslot = fcg + s * 32;
        for (int k = 0; k < 128; k++) {
            // ---- chunk gate: L0 done through t=8k+7; ring slots free ----
            if (tid < 64) {
                const uint* fp; uint tgt;
                int sl = l & 15;
                if (sl < 8) { fp = f0g + sl * 32; tgt = (uint)(8 * k + 8); }
                else        { fp = f1g + (sl - 8) * 32; tgt = (k >= 2) ? (uint)(8 * k - 8) : 0u; }
                poll_all(fp, tgt);
                if (l == 0)
                    (void)__hip_atomic_load(f0g, __ATOMIC_ACQUIRE, __HIP_MEMORY_SCOPE_AGENT);
            }
            __syncthreads();
            for (int tt = 0; tt < 8; tt++) {
                int t = 8 * k + tt;
                const char* src = (const char*)(cbuf + (t * 64 + g * 16) * 1024);
                u32x4 v[8];
#pragma unroll
                for (int i = 0; i < 8; i++)
                    v[i] = *(const u32x4*)(src + tid * 16 + i * 4096);
                __syncthreads();   // prev GEMM reads done before overwrite
#pragma unroll
                for (int i = 0; i < 8; i++) {
                    int off = tid * 16 + i * 4096;
                    int row = off >> 11;
                    int sw = (off & 2047) ^ ((row & 7) << 4);
                    *(u32x4*)(lds + row * 2048 + sw) = v[i];
                }
                __syncthreads();
                f32x4 a0c = (f32x4){0.f,0.f,0.f,0.f}, a1c = (f32x4){0.f,0.f,0.f,0.f};
#pragma unroll
                for (int kc = 0; kc < 32; kc += 2) {
                    int b0 = (kc * 64 + lq * 16) ^ ((lr & 7) << 4);
                    int b1 = ((kc + 1) * 64 + lq * 16) ^ ((lr & 7) << 4);
                    s16x8 fA = *(const s16x8*)(lds + lr * 2048 + b0);
                    s16x8 fB = *(const s16x8*)(lds + lr * 2048 + b1);
                    a0c = __builtin_amdgcn_mfma_f32_16x16x32_bf16(fA, wgtA[kc], a0c, 0, 0, 0);
                    a1c = __builtin_amdgcn_mfma_f32_16x16x32_bf16(fB, wgtA[kc + 1], a1c, 0, 0, 0);
                }
                // write c1 slot (f32): ring[((g*16+s)*16 + (t&15))*1024 + row*64 + c64]
                float* rd = ring + (long long)((g * 16 + s) * 16 + (t & 15)) * 1024
                          + (wv * 16 + lr);
#pragma unroll
                for (int j = 0; j < 4; j++)
                    rd[(lq * 4 + j) * 64] = a0c[j] + a1c[j] + bb;
            }
            __syncthreads();       // drain ring stores (vmcnt) across all waves
            if (tid == 0)
                __hip_atomic_store(myslot, (uint)(8 * k + 8), __ATOMIC_RELEASE,
                                   __HIP_MEMORY_SCOPE_AGENT);
        }
        return;
    }

    // ---- roles 0 (L0) and 2 (L1): serial recurrence, 128 cols/WG ----
    uint* myslot = ((role == 0) ? f0g : f1g) + s * 32;
    const ushort* hinit = hinitb + (role == 2 ? 65536 : 0) + g * 16 * 1024;

    for (int t = 0; t < 1024; t++) {
        int cbase = (t * 64 + g * 16) * 1024;

        ushort cfA[4], cfB[4];
        if (role == 0) {
            // prefetch own-col c0[t] (proj0 output, stable) before the gate
#pragma unroll
            for (int j = 0; j < 4; j++) {
                cfA[j] = cbuf[cbase + (lq * 4 + j) * 1024 + colA];
                cfB[j] = cbuf[cbase + (lq * 4 + j) * 1024 + colB];
            }
        }

        // ---- gate ----
        if (tid < 64) {
            if (role == 0) {
                poll_all(f0g + (l & 7) * 32, (uint)t);
            } else {
                const uint* fp; uint tgt;
                int sl = l & 15;
                if (sl < 8) { fp = f1g + sl * 32; tgt = (uint)t; }
                else if (sl < 10) { fp = fcg + (2 * s + (sl - 8)) * 32; tgt = (uint)(t + 1); }
                else { fp = f1g; tgt = (uint)t; }
                poll_all(fp, tgt);
            }
            if (l == 0)
                (void)__hip_atomic_load(f0g, __ATOMIC_ACQUIRE, __HIP_MEMORY_SCOPE_AGENT);
        }
        __syncthreads();

        // ---- c1 ring reads (role 2, after acquire) ----
        float c1A[4], c1B[4];
        if (role == 2) {
            const float* rA = ring + (long long)((g * 16 + 2 * s) * 16 + (t & 15)) * 1024
                            + (wv * 16 + lr);
            const float* rB = ring + (long long)((g * 16 + 2 * s + 1) * 16 + (t & 15)) * 1024
                            + (wv * 16 + lr);
#pragma unroll
            for (int j = 0; j < 4; j++) {
                c1A[j] = rA[(lq * 4 + j) * 64];
                c1B[j] = rB[(lq * 4 + j) * 64];
            }
        }

        // ---- stage h_{t-1} (16 x 1024 bf16) ----
        const char* src;
        if (role == 0)
            src = (const char*)((t == 0) ? hinit
                                         : (cbuf + ((t - 1) * 64 + g * 16) * 1024));
        else
            src = (const char*)((t == 0) ? hinit
                                         : (hdb1 + ((t - 1) & 1) * 65536 + g * 16 * 1024));
#pragma unroll
        for (int i = 0; i < 8; i++) {
            int off = tid * 16 + i * 4096;
            u32x4 v = *(const u32x4*)(src + off);
            int row = off >> 11;
            int sw = (off & 2047) ^ ((row & 7) << 4);
            *(u32x4*)(lds + row * 2048 + sw) = v;
        }
        __syncthreads();

        // ---- GEMM: 64 MFMAs (2 col-fragments), 4 chains ----
        f32x4 aA0 = (f32x4){0.f,0.f,0.f,0.f}, aA1 = (f32x4){0.f,0.f,0.f,0.f};
        f32x4 aB0 = (f32x4){0.f,0.f,0.f,0.f}, aB1 = (f32x4){0.f,0.f,0.f,0.f};
#pragma unroll
        for (int kc = 0; kc < 32; kc += 2) {
            int b0 = (kc * 64 + lq * 16) ^ ((lr & 7) << 4);
            int b1 = ((kc + 1) * 64 + lq * 16) ^ ((lr & 7) << 4);
            s16x8 h0 = *(const s16x8*)(lds + lr * 2048 + b0);
            s16x8 h1 = *(const s16x8*)(lds + lr * 2048 + b1);
            aA0 = __builtin_amdgcn_mfma_f32_16x16x32_bf16(h0, wgtA[kc], aA0, 0, 0, 0);
            aB0 = __builtin_amdgcn_mfma_f32_16x16x32_bf16(h0, wgtB[kc], aB0, 0, 0, 0);
            aA1 = __builtin_amdgcn_mfma_f32_16x16x32_bf16(h1, wgtA[kc + 1], aA1, 0, 0, 0);
            aB1 = __builtin_amdgcn_mfma_f32_16x16x32_bf16(h1, wgtB[kc + 1], aB1, 0, 0, 0);
        }

        float hnA[4], hnB[4];
#pragma unroll
        for (int j = 0; j < 4; j++) {
            float zA = aA0[j] + aA1[j] + (role == 0 ? bf2f(cfA[j]) : c1A[j]);
            float zB = aB0[j] + aB1[j] + (role == 0 ? bf2f(cfB[j]) : c1B[j]);
            zA = fminf(fmaxf(zA, -15.f), 15.f);
            zB = fminf(fmaxf(zB, -15.f), 15.f);
            float eA = __expf(2.f * zA), eB = __expf(2.f * zB);
            hnA[j] = (eA - 1.f) / (eA + 1.f);
            hnB[j] = (eB - 1.f) / (eB + 1.f);
        }

        // ---- publish (plain stores) ----
        if (role == 0) {
#pragma unroll
            for (int j = 0; j < 4; j++) {
                cbuf[cbase + (lq * 4 + j) * 1024 + colA] = f2bf(hnA[j]);
                cbuf[cbase + (lq * 4 + j) * 1024 + colB] = f2bf(hnB[j]);
            }
        } else {
            ushort* hdst = hdb1 + (t & 1) * 65536 + g * 16 * 1024;
#pragma unroll
            for (int j = 0; j < 4; j++) {
                hdst[(lq * 4 + j) * 1024 + colA] = f2bf(hnA[j]);
                hdst[(lq * 4 + j) * 1024 + colB] = f2bf(hnB[j]);
            }
            float sA = hnA[0] + hnA[1] + hnA[2] + hnA[3];
            float sB = hnB[0] + hnB[1] + hnB[2] + hnB[3];
            sA += __shfl_xor(sA, 16); sA += __shfl_xor(sA, 32);
            sB += __shfl_xor(sB, 16); sB += __shfl_xor(sB, 32);
            if (l < 16) {
                ppart[(g * 1024 + t) * 1024 + colA] = sA;
                ppart[(g * 1024 + t) * 1024 + colB] = sB;
            }
        }

        __syncthreads();       // each wave drains vmcnt; protects LDS WAR too
        if (tid == 0)
            __hip_atomic_store(myslot, (uint)(t + 1), __ATOMIC_RELEASE,
                               __HIP_MEMORY_SCOPE_AGENT);
    }
}

// ---------------- head ----------------
__launch_bounds__(256)
__global__ void k_head(const float* __restrict__ W1, const float* __restrict__ b1,
                       const float* __restrict__ W2, const float* __restrict__ b2,
                       char* ws, float* __restrict__ out) {
    const float* pp = (const float*)(ws + OFF_PPART);
    int bx = blockIdx.x;
    int t0 = bx * 8;
    int tid = threadIdx.x;

    __shared__ float pl[8][1024];
    __shared__ float red[256][8];

    for (int i = tid; i < 8192; i += 256) {
        int tt = i >> 10, k = i & 1023;
        int base = (t0 + tt) * 1024 + k;
        float s = pp[base] + pp[1048576 + base] + pp[2097152 + base] + pp[3145728 + base];
        pl[tt][k] = s * (1.f / 64.f);
    }
    __syncthreads();

    float po[8];
#pragma unroll
    for (int tt = 0; tt < 8; tt++) po[tt] = 0.f;

    for (int jj = 0; jj < 2; jj++) {
        int j = tid + jj * 256;
        float accv[8];
        float bias = b1[j];
#pragma unroll
        for (int tt = 0; tt < 8; tt++) accv[tt] = bias;
        const float* wr = W1 + (long long)j * 1024;
        for (int k = 0; k < 1024; k += 8) {
            f32x4 wa = *(const f32x4*)(wr + k);
            f32x4 wb = *(const f32x4*)(wr + k + 4);
#pragma unroll
            for (int tt = 0; tt < 8; tt++) {
                accv[tt] += pl[tt][k] * wa[0] + pl[tt][k + 1] * wa[1] +
                            pl[tt][k + 2] * wa[2] + pl[tt][k + 3] * wa[3] +
                            pl[tt][k + 4] * wb[0] + pl[tt][k + 5] * wb[1] +
                            pl[tt][k + 6] * wb[2] + pl[tt][k + 7] * wb[3];
            }
        }
        float w2 = W2[j];
#pragma unroll
        for (int tt = 0; tt < 8; tt++) po[tt] += fmaxf(accv[tt], 0.f) * w2;
    }

#pragma unroll
    for (int tt = 0; tt < 8; tt++) red[tid][tt] = po[tt];
    __syncthreads();
    for (int st = 128; st >= 1; st >>= 1) {
        if (tid < st) {
#pragma unroll
            for (int tt = 0; tt < 8; tt++) red[tid][tt] += red[tid + st][tt];
        }
        __syncthreads();
    }
    if (tid < 8) out[t0 + tid] = 1.f / (1.f + __expf(-(red[0][tid] + b2[0])));
}

extern "C" void kernel_launch(void* const* d_in, const int* in_sizes, int n_in,
                              void* d_out, int out_size, void* d_ws, size_t ws_size,
                              hipStream_t stream) {
    const float* x    = (const float*)d_in[0];
    const float* hid  = (const float*)d_in[1];
    const float* Wih0 = (const float*)d_in[2];
    const float* Whh0 = (const float*)d_in[3];
    const float* bih0 = (const float*)d_in[4];
    const float* bhh0 = (const float*)d_in[5];
    const float* Wih1 = (const float*)d_in[6];
    const float* Whh1 = (const float*)d_in[7];
    const float* bih1 = (const float*)d_in[8];
    const float* bhh1 = (const float*)d_in[9];
    const float* W1   = (const float*)d_in[10];
    const float* b1   = (const float*)d_in[11];
    const float* W2   = (const float*)d_in[12];
    const float* b2   = (const float*)d_in[13];
    char* ws = (char*)d_ws;
    float* out = (float*)d_out;

    hipLaunchKernelGGL(k_prep, dim3(1024), dim3(256), 0, stream,
                       Wih0, Whh0, Wih1, Whh1, hid, ws);
    hipLaunchKernelGGL(k_proj0, dim3(4096), dim3(256), 0, stream, x, bih0, bhh0, ws);
    hipLaunchKernelGGL(k_recf, dim3(128), dim3(256), 0, stream,
                       (const ushort*)(ws + OFF_WH0B), (const ushort*)(ws + OFF_WH1B),
                       (const ushort*)(ws + OFF_W1B),
                       (ushort*)(ws + OFF_BUF), (ushort*)(ws + OFF_HDB1),
                       (const ushort*)(ws + OFF_HINIT), (uint*)(ws + OFF_FLG),
                       (float*)(ws + OFF_RING), (float*)(ws + OFF_PPART),
                       bih1, bhh1);
    hipLaunchKernelGGL(k_head, dim3(128), dim3(256), 0, stream, W1, b1, W2, b2, ws, out);
}

// Round 10
// 6573.694 us; speedup vs baseline: 3.8680x; 1.2260x over previous
//
#include <hip/hip_runtime.h>

typedef unsigned int uint;
typedef unsigned short ushort;
typedef unsigned long long u64;
typedef __attribute__((ext_vector_type(8))) short s16x8;
typedef __attribute__((ext_vector_type(4))) float f32x4;
typedef __attribute__((ext_vector_type(4))) uint u32x4;

// problem dims (fixed)
#define SEQ 1024
#define BATCH 64
#define INDIM 512
#define HID 1024

// ---- workspace layout (bytes) ----
#define OFF_BUF   0ull
#define SZ_BUF    (65536ull * 1024ull * 2ull)           // c0 -> r0 (in-place), bf16
#define OFF_W0B   (OFF_BUF + SZ_BUF)                    // W_ih0 bf16 (1024x512)
#define OFF_WH0B  (OFF_W0B  + 1048576ull)               // W_hh0 bf16
#define OFF_W1B   (OFF_WH0B + 2097152ull)               // W_ih1 bf16
#define OFF_WH1B  (OFF_W1B  + 2097152ull)               // W_hh1 bf16
#define OFF_HINIT (OFF_WH1B + 2097152ull)               // hidden bf16 [2][64][1024]
#define OFF_HDB1  (OFF_HINIT + 262144ull)               // L1 h double buffer [2][64][1024]
#define OFF_FLG   (OFF_HDB1 + 262144ull)                // flag sets, 128B-padded slots
#define OFF_RING  (OFF_FLG + 131072ull)                 // c1 ring [4][16][16][16][64] f32 = 4MB
#define OFF_PPART (OFF_RING + 4194304ull)               // pooled partials [4][1024][1024] f32
#define WS_NEEDED (OFF_PPART + 16777216ull)

__device__ __forceinline__ ushort f2bf(float f) {
    uint u = __float_as_uint(f);
    uint r = (u + 0x7fffu + ((u >> 16) & 1u)) >> 16;
    return (ushort)r;
}
__device__ __forceinline__ float bf2f(ushort h) {
    return __uint_as_float(((uint)h) << 16);
}

// write-through stores (update IF; leave no dirty L2 lines -> release wbl2 cheap)
__device__ __forceinline__ void st16wt(void* p, uint v) {
    asm volatile("global_store_short %0, %1, off sc0 sc1"
                 :: "v"((u64)p), "v"(v) : "memory");
}
__device__ __forceinline__ void stf32wt(float* p, float v) {
    asm volatile("global_store_dword %0, %1, off sc0 sc1"
                 :: "v"((u64)p), "v"(v) : "memory");
}

// each lane polls its own fp until >= tgt (monotone counters)
__device__ __forceinline__ void poll_all(const uint* fp, uint tgt) {
    for (;;) {
        uint v = __hip_atomic_load(fp, __ATOMIC_RELAXED, __HIP_MEMORY_SCOPE_AGENT);
        if (__all(v >= tgt)) break;
        __builtin_amdgcn_s_sleep(1);
    }
}

// ---------------- prep ----------------
__global__ void k_prep(const float* Wih0, const float* Whh0, const float* Wih1,
                       const float* Whh1, const float* hid, char* ws) {
    ushort* w0  = (ushort*)(ws + OFF_W0B);
    ushort* wh0 = (ushort*)(ws + OFF_WH0B);
    ushort* w1  = (ushort*)(ws + OFF_W1B);
    ushort* wh1 = (ushort*)(ws + OFF_WH1B);
    ushort* hi  = (ushort*)(ws + OFF_HINIT);
    uint*   flg = (uint*)(ws + OFF_FLG);
    const long long total = 524288 + 3 * 1048576 + 131072 + 32768;
    for (long long i = (long long)blockIdx.x * 256 + threadIdx.x; i < total;
         i += (long long)gridDim.x * 256) {
        long long j = i;
        if (j < 524288)  { w0[j]  = f2bf(Wih0[j]); continue; }  j -= 524288;
        if (j < 1048576) { wh0[j] = f2bf(Whh0[j]); continue; }  j -= 1048576;
        if (j < 1048576) { w1[j]  = f2bf(Wih1[j]); continue; }  j -= 1048576;
        if (j < 1048576) { wh1[j] = f2bf(Whh1[j]); continue; }  j -= 1048576;
        if (j < 131072)  { hi[j]  = f2bf(hid[j]);  continue; }  j -= 131072;
        flg[j] = 0u;
    }
}

// ---------------- proj0 ----------------
__launch_bounds__(256)
__global__ void k_proj0(const float* __restrict__ x, const float* __restrict__ bih,
                        const float* __restrict__ bhh, char* ws) {
    const ushort* W = (const ushort*)(ws + OFF_W0B);
    ushort* cbuf = (ushort*)(ws + OFF_BUF);
    int bx = blockIdx.x;
    int mtile = bx >> 2, ntile = bx & 3;
    int tid = threadIdx.x, w = tid >> 6, l = tid & 63;
    int lr = l & 15, lq = l >> 4;
    int arow = mtile * 64 + w * 16 + lr;

    f32x4 acc[16];
#pragma unroll
    for (int i = 0; i < 16; i++) acc[i] = (f32x4){0.f, 0.f, 0.f, 0.f};

    for (int kc = 0; kc < 16; kc++) {
        int k0 = kc * 32 + lq * 8;
        const f32x4* ap = (const f32x4*)(x + (long long)arow * 512 + k0);
        f32x4 a0 = ap[0], a1 = ap[1];
        s16x8 a;
        a[0] = (short)f2bf(a0[0]); a[1] = (short)f2bf(a0[1]);
        a[2] = (short)f2bf(a0[2]); a[3] = (short)f2bf(a0[3]);
        a[4] = (short)f2bf(a1[0]); a[5] = (short)f2bf(a1[1]);
        a[6] = (short)f2bf(a1[2]); a[7] = (short)f2bf(a1[3]);
#pragma unroll
        for (int nf = 0; nf < 16; nf++) {
            int col = ntile * 256 + nf * 16 + lr;
            s16x8 b = *(const s16x8*)(W + (long long)col * 512 + k0);
            acc[nf] = __builtin_amdgcn_mfma_f32_16x16x32_bf16(a, b, acc[nf], 0, 0, 0);
        }
    }
#pragma unroll
    for (int nf = 0; nf < 16; nf++) {
        int col = ntile * 256 + nf * 16 + lr;
        float bb = bih[col] + bhh[col];
#pragma unroll
        for (int j = 0; j < 4; j++) {
            int row = mtile * 64 + w * 16 + lq * 4 + j;
            cbuf[(long long)row * 1024 + col] = f2bf(acc[nf][j] + bb);
        }
    }
}

// ---------------- fused pipeline: L0 | chunked-proj1 | L1 ----------------
// grid 128 x 256.  xcd = wgid&7, hi = wgid>>3.
//  xcd<4 : g=xcd;  hi<8 -> role0 (L0, s=hi);  hi>=8 -> role2 (L1, s=hi-8)
//  xcd>=4: role1 (proj1), g=xcd-4, s=hi (0..15)
// Publish: WRITE-THROUGH (sc0 sc1) data stores -> __syncthreads -> lane-0
// RELEASE (wbl2 now ~empty).  Consume: relaxed poll -> lane-0 ACQUIRE
// (buffer_inv drops stale lines) -> __syncthreads -> plain loads.
__launch_bounds__(256, 1)
__global__ void k_recf(const ushort* __restrict__ wh0p, const ushort* __restrict__ wh1p,
                       const ushort* __restrict__ wxp,
                       ushort* __restrict__ cbuf, ushort* __restrict__ hdb1,
                       const ushort* __restrict__ hinitb, uint* __restrict__ flg,
                       float* __restrict__ ring, float* __restrict__ ppart,
                       const float* __restrict__ bih1, const float* __restrict__ bhh1) {
    int wgid = blockIdx.x;
    int x = wgid & 7, hi = wgid >> 3;
    int role, g, s;
    if (x < 4) { g = x; if (hi < 8) { role = 0; s = hi; } else { role = 2; s = hi - 8; } }
    else       { role = 1; g = x - 4; s = hi; }

    int tid = threadIdx.x;
    int l = tid & 63, wv = tid >> 6, lr = l & 15, lq = l >> 4;

    uint* f0g = flg + (g * 8) * 32;            // L0 flags: 8 slots/group
    uint* f1g = flg + 1024 + (g * 8) * 32;     // L1 flags: 8 slots/group
    uint* fcg = flg + 2048 + (g * 16) * 32;    // proj1 flags: 16 slots/group

    __shared__ __align__(16) char lds[32768];

    // weight fragments (B-layout: B[k][col] = W[col][k])
    int colA = (role == 1) ? (s * 64 + wv * 16 + lr) : (s * 128 + wv * 16 + lr);
    int colB = (role == 1) ? colA : (s * 128 + 64 + wv * 16 + lr);
    const ushort* Wb = (role == 0) ? wh0p : (role == 1) ? wxp : wh1p;

    s16x8 wgtA[32], wgtB[32];
#pragma unroll
    for (int kc = 0; kc < 32; kc++)
        wgtA[kc] = *(const s16x8*)(Wb + (long long)colA * 1024 + kc * 32 + lq * 8);
#pragma unroll
    for (int kc = 0; kc < 32; kc++) asm volatile("" : "+v"(wgtA[kc]));
    if (role != 1) {
#pragma unroll
        for (int kc = 0; kc < 32; kc++)
            wgtB[kc] = *(const s16x8*)(Wb + (long long)colB * 1024 + kc * 32 + lq * 8);
#pragma unroll
        for (int kc = 0; kc < 32; kc++) asm volatile("" : "+v"(wgtB[kc]));
    }

    if (role == 1) {
        float bb = bih1[colA] + bhh1[colA];
        uint* myslot = fcg + s * 32;
        for (int k = 0; k < 128; k++) {
            // ---- chunk gate: L0 done through t=8k+7; ring slots free ----
            if (tid < 64) {
                const uint* fp; uint tgt;
                int sl = l & 15;
                if (sl < 8) { fp = f0g + sl * 32; tgt = (uint)(8 * k + 8); }
                else        { fp = f1g + (sl - 8) * 32; tgt = (k >= 2) ? (uint)(8 * k - 8) : 0u; }
                poll_all(fp, tgt);
                if (l == 0)
                    (void)__hip_atomic_load(f0g, __ATOMIC_ACQUIRE, __HIP_MEMORY_SCOPE_AGENT);
            }
            __syncthreads();
            for (int tt = 0; tt < 8; tt++) {
                int t = 8 * k + tt;
                const char* src = (const char*)(cbuf + (t * 64 + g * 16) * 1024);
                u32x4 v[8];
#pragma unroll
                for (int i = 0; i < 8; i++)
                    v[i] = *(const u32x4*)(src + tid * 16 + i * 4096);
                __syncthreads();   // prev GEMM reads done before overwrite
#pragma unroll
                for (int i = 0; i < 8; i++) {
                    int off = tid * 16 + i * 4096;
                    int row = off >> 11;
                    int sw = (off & 2047) ^ ((row & 7) << 4);
                    *(u32x4*)(lds + row * 2048 + sw) = v[i];
                }
                __syncthreads();
                f32x4 a0c = (f32x4){0.f,0.f,0.f,0.f}, a1c = (f32x4){0.f,0.f,0.f,0.f};
#pragma unroll
                for (int kc = 0; kc < 32; kc += 2) {
                    int b0 = (kc * 64 + lq * 16) ^ ((lr & 7) << 4);
                    int b1 = ((kc + 1) * 64 + lq * 16) ^ ((lr & 7) << 4);
                    s16x8 fA = *(const s16x8*)(lds + lr * 2048 + b0);
                    s16x8 fB = *(const s16x8*)(lds + lr * 2048 + b1);
                    a0c = __builtin_amdgcn_mfma_f32_16x16x32_bf16(fA, wgtA[kc], a0c, 0, 0, 0);
                    a1c = __builtin_amdgcn_mfma_f32_16x16x32_bf16(fB, wgtA[kc + 1], a1c, 0, 0, 0);
                }
                // write c1 slot (f32, write-through)
                float* rd = ring + (long long)((g * 16 + s) * 16 + (t & 15)) * 1024
                          + (wv * 16 + lr);
#pragma unroll
                for (int j = 0; j < 4; j++)
                    stf32wt(rd + (lq * 4 + j) * 64, a0c[j] + a1c[j] + bb);
            }
            __syncthreads();       // drain write-through stores (vmcnt) all waves
            if (tid == 0)
                __hip_atomic_store(myslot, (uint)(8 * k + 8), __ATOMIC_RELEASE,
                                   __HIP_MEMORY_SCOPE_AGENT);
        }
        return;
    }

    // ---- roles 0 (L0) and 2 (L1): serial recurrence, 128 cols/WG ----
    uint* myslot = ((role == 0) ? f0g : f1g) + s * 32;
    const ushort* hinit = hinitb + (role == 2 ? 65536 : 0) + g * 16 * 1024;

    for (int t = 0; t < 1024; t++) {
        int cbase = (t * 64 + g * 16) * 1024;

        ushort cfA[4], cfB[4];
        if (role == 0) {
            // prefetch own-col c0[t] (proj0 output, stable) before the gate
#pragma unroll
            for (int j = 0; j < 4; j++) {
                cfA[j] = cbuf[cbase + (lq * 4 + j) * 1024 + colA];
                cfB[j] = cbuf[cbase + (lq * 4 + j) * 1024 + colB];
            }
        }

        // ---- gate ----
        if (tid < 64) {
            if (role == 0) {
                poll_all(f0g + (l & 7) * 32, (uint)t);
            } else {
                const uint* fp; uint tgt;
                int sl = l & 15;
                if (sl < 8) { fp = f1g + sl * 32; tgt = (uint)t; }
                else if (sl < 10) { fp = fcg + (2 * s + (sl - 8)) * 32; tgt = (uint)(t + 1); }
                else { fp = f1g; tgt = (uint)t; }
                poll_all(fp, tgt);
            }
            if (l == 0)
                (void)__hip_atomic_load(f0g, __ATOMIC_ACQUIRE, __HIP_MEMORY_SCOPE_AGENT);
        }
        __syncthreads();

        // ---- c1 ring reads (role 2, after acquire) ----
        float c1A[4], c1B[4];
        if (role == 2) {
            const float* rA = ring + (long long)((g * 16 + 2 * s) * 16 + (t & 15)) * 1024
                            + (wv * 16 + lr);
            const float* rB = ring + (long long)((g * 16 + 2 * s + 1) * 16 + (t & 15)) * 1024
                            + (wv * 16 + lr);
#pragma unroll
            for (int j = 0; j < 4; j++) {
                c1A[j] = rA[(lq * 4 + j) * 64];
                c1B[j] = rB[(lq * 4 + j) * 64];
            }
        }

        // ---- stage h_{t-1} (16 x 1024 bf16) ----
        const char* src;
        if (role == 0)
            src = (const char*)((t == 0) ? hinit
                                         : (cbuf + ((t - 1) * 64 + g * 16) * 1024));
        else
            src = (const char*)((t == 0) ? hinit
                                         : (hdb1 + ((t - 1) & 1) * 65536 + g * 16 * 1024));
#pragma unroll
        for (int i = 0; i < 8; i++) {
            int off = tid * 16 + i * 4096;
            u32x4 v = *(const u32x4*)(src + off);
            int row = off >> 11;
            int sw = (off & 2047) ^ ((row & 7) << 4);
            *(u32x4*)(lds + row * 2048 + sw) = v;
        }
        __syncthreads();

        // ---- GEMM: 64 MFMAs (2 col-fragments), 4 chains ----
        f32x4 aA0 = (f32x4){0.f,0.f,0.f,0.f}, aA1 = (f32x4){0.f,0.f,0.f,0.f};
        f32x4 aB0 = (f32x4){0.f,0.f,0.f,0.f}, aB1 = (f32x4){0.f,0.f,0.f,0.f};
#pragma unroll
        for (int kc = 0; kc < 32; kc += 2) {
            int b0 = (kc * 64 + lq * 16) ^ ((lr & 7) << 4);
            int b1 = ((kc + 1) * 64 + lq * 16) ^ ((lr & 7) << 4);
            s16x8 h0 = *(const s16x8*)(lds + lr * 2048 + b0);
            s16x8 h1 = *(const s16x8*)(lds + lr * 2048 + b1);
            aA0 = __builtin_amdgcn_mfma_f32_16x16x32_bf16(h0, wgtA[kc], aA0, 0, 0, 0);
            aB0 = __builtin_amdgcn_mfma_f32_16x16x32_bf16(h0, wgtB[kc], aB0, 0, 0, 0);
            aA1 = __builtin_amdgcn_mfma_f32_16x16x32_bf16(h1, wgtA[kc + 1], aA1, 0, 0, 0);
            aB1 = __builtin_amdgcn_mfma_f32_16x16x32_bf16(h1, wgtB[kc + 1], aB1, 0, 0, 0);
        }

        float hnA[4], hnB[4];
#pragma unroll
        for (int j = 0; j < 4; j++) {
            float zA = aA0[j] + aA1[j] + (role == 0 ? bf2f(cfA[j]) : c1A[j]);
            float zB = aB0[j] + aB1[j] + (role == 0 ? bf2f(cfB[j]) : c1B[j]);
            zA = fminf(fmaxf(zA, -15.f), 15.f);
            zB = fminf(fmaxf(zB, -15.f), 15.f);
            float eA = __expf(2.f * zA), eB = __expf(2.f * zB);
            hnA[j] = (eA - 1.f) / (eA + 1.f);
            hnB[j] = (eB - 1.f) / (eB + 1.f);
        }

        // ---- publish (write-through stores) ----
        if (role == 0) {
#pragma unroll
            for (int j = 0; j < 4; j++) {
                st16wt(cbuf + cbase + (lq * 4 + j) * 1024 + colA, (uint)f2bf(hnA[j]));
                st16wt(cbuf + cbase + (lq * 4 + j) * 1024 + colB, (uint)f2bf(hnB[j]));
            }
        } else {
            ushort* hdst = hdb1 + (t & 1) * 65536 + g * 16 * 1024;
#pragma unroll
            for (int j = 0; j < 4; j++) {
                st16wt(hdst + (lq * 4 + j) * 1024 + colA, (uint)f2bf(hnA[j]));
                st16wt(hdst + (lq * 4 + j) * 1024 + colB, (uint)f2bf(hnB[j]));
            }
            float sA = hnA[0] + hnA[1] + hnA[2] + hnA[3];
            float sB = hnB[0] + hnB[1] + hnB[2] + hnB[3];
            sA += __shfl_xor(sA, 16); sA += __shfl_xor(sA, 32);
            sB += __shfl_xor(sB, 16); sB += __shfl_xor(sB, 32);
            if (l < 16) {
                stf32wt(&ppart[(g * 1024 + t) * 1024 + colA], sA);
                stf32wt(&ppart[(g * 1024 + t) * 1024 + colB], sB);
            }
        }

        __syncthreads();       // each wave drains vmcnt; protects LDS WAR too
        if (tid == 0)
            __hip_atomic_store(myslot, (uint)(t + 1), __ATOMIC_RELEASE,
                               __HIP_MEMORY_SCOPE_AGENT);
    }
}

// ---------------- head ----------------
__launch_bounds__(256)
__global__ void k_head(const float* __restrict__ W1, const float* __restrict__ b1,
                       const float* __restrict__ W2, const float* __restrict__ b2,
                       char* ws, float* __restrict__ out) {
    const float* pp = (const float*)(ws + OFF_PPART);
    int bx = blockIdx.x;
    int t0 = bx * 8;
    int tid = threadIdx.x;

    __shared__ float pl[8][1024];
    __shared__ float red[256][8];

    for (int i = tid; i < 8192; i += 256) {
        int tt = i >> 10, k = i & 1023;
        int base = (t0 + tt) * 1024 + k;
        float s = pp[base] + pp[1048576 + base] + pp[2097152 + base] + pp[3145728 + base];
        pl[tt][k] = s * (1.f / 64.f);
    }
    __syncthreads();

    float po[8];
#pragma unroll
    for (int tt = 0; tt < 8; tt++) po[tt] = 0.f;

    for (int jj = 0; jj < 2; jj++) {
        int j = tid + jj * 256;
        float accv[8];
        float bias = b1[j];
#pragma unroll
        for (int tt = 0; tt < 8; tt++) accv[tt] = bias;
        const float* wr = W1 + (long long)j * 1024;
        for (int k = 0; k < 1024; k += 8) {
            f32x4 wa = *(const f32x4*)(wr + k);
            f32x4 wb = *(const f32x4*)(wr + k + 4);
#pragma unroll
            for (int tt = 0; tt < 8; tt++) {
                accv[tt] += pl[tt][k] * wa[0] + pl[tt][k + 1] * wa[1] +
                            pl[tt][k + 2] * wa[2] + pl[tt][k + 3] * wa[3] +
                            pl[tt][k + 4] * wb[0] + pl[tt][k + 5] * wb[1] +
                            pl[tt][k + 6] * wb[2] + pl[tt][k + 7] * wb[3];
            }
        }
        float w2 = W2[j];
#pragma unroll
        for (int tt = 0; tt < 8; tt++) po[tt] += fmaxf(accv[tt], 0.f) * w2;
    }

#pragma unroll
    for (int tt = 0; tt < 8; tt++) red[tid][tt] = po[tt];
    __syncthreads();
    for (int st = 128; st >= 1; st >>= 1) {
        if (tid < st) {
#pragma unroll
            for (int tt = 0; tt < 8; tt++) red[tid][tt] += red[tid + st][tt];
        }
        __syncthreads();
    }
    if (tid < 8) out[t0 + tid] = 1.f / (1.f + __expf(-(red[0][tid] + b2[0])));
}

extern "C" void kernel_launch(void* const* d_in, const int* in_sizes, int n_in,
                              void* d_out, int out_size, void* d_ws, size_t ws_size,
                              hipStream_t stream) {
    const float* x    = (const float*)d_in[0];
    const float* hid  = (const float*)d_in[1];
    const float* Wih0 = (const float*)d_in[2];
    const float* Whh0 = (const float*)d_in[3];
    const float* bih0 = (const float*)d_in[4];
    const float* bhh0 = (const float*)d_in[5];
    const float* Wih1 = (const float*)d_in[6];
    const float* Whh1 = (const float*)d_in[7];
    const float* bih1 = (const float*)d_in[8];
    const float* bhh1 = (const float*)d_in[9];
    const float* W1   = (const float*)d_in[10];
    const float* b1   = (const float*)d_in[11];
    const float* W2   = (const float*)d_in[12];
    const float* b2   = (const float*)d_in[13];
    char* ws = (char*)d_ws;
    float* out = (float*)d_out;

    hipLaunchKernelGGL(k_prep, dim3(1024), dim3(256), 0, stream,
                       Wih0, Whh0, Wih1, Whh1, hid, ws);
    hipLaunchKernelGGL(k_proj0, dim3(4096), dim3(256), 0, stream, x, bih0, bhh0, ws);
    hipLaunchKernelGGL(k_recf, dim3(128), dim3(256), 0, stream,
                       (const ushort*)(ws + OFF_WH0B), (const ushort*)(ws + OFF_WH1B),
                       (const ushort*)(ws + OFF_W1B),
                       (ushort*)(ws + OFF_BUF), (ushort*)(ws + OFF_HDB1),
                       (const ushort*)(ws + OFF_HINIT), (uint*)(ws + OFF_FLG),
                       (float*)(ws + OFF_RING), (float*)(ws + OFF_PPART),
                       bih1, bhh1);
    hipLaunchKernelGGL(k_head, dim3(128), dim3(256), 0, stream, W1, b1, W2, b2, ws, out);
}